// Round 5
// baseline (1458.923 us; speedup 1.0000x reference)
//
#include <hip/hip_runtime.h>
#include <math.h>

#define TPB 256

constexpr int Dd = 256;
constexpr int Nn = 1024;
constexpr int Mm = 1025;      // Nn + 1 (with dustbin)
constexpr int LDKc = 1040;    // padded row stride for K / KT (16-float aligned)
constexpr int SINK_ITERS = 100;

// ---- workspace layout (float offsets) ----
constexpr size_t OF_MD0   = 0;
constexpr size_t OF_MD1   = OF_MD0  + (size_t)Dd*Nn;
constexpr size_t OF_MD0T  = OF_MD1  + (size_t)Dd*Nn;
constexpr size_t OF_MD1T  = OF_MD0T + (size_t)Dd*Nn;
constexpr size_t OF_HA    = OF_MD1T + (size_t)Dd*Nn;
constexpr size_t OF_HBT   = OF_HA   + (size_t)Nn*64;
constexpr size_t OF_ZFA   = OF_HBT  + (size_t)Nn*64;
constexpr size_t OF_ZFB   = OF_ZFA  + (size_t)Nn*Dd;
constexpr size_t OF_WZ1T  = OF_ZFB  + (size_t)Nn*Dd;
constexpr size_t OF_WZ2T  = OF_WZ1T + (size_t)Dd*Dd;
constexpr size_t OF_ZA    = OF_WZ2T + (size_t)64*Dd;
constexpr size_t OF_ZB    = OF_ZA   + Nn;
constexpr size_t OF_ROWM  = OF_ZB   + Nn;
constexpr size_t OF_ROWS  = OF_ROWM + Nn;
constexpr size_t OF_CMP   = OF_ROWS + Nn;        // 16 x 1024 column partial max
constexpr size_t OF_CSP   = OF_CMP  + (size_t)16*Nn;
constexpr size_t OF_COLM  = OF_CSP  + (size_t)16*Nn;
constexpr size_t OF_COLS  = OF_COLM + Nn;
constexpr size_t OF_AMP   = OF_COLS + Nn;             // col-argmax partial max
constexpr size_t OF_AIP   = OF_AMP  + (size_t)16*Nn;  // col-argmax partial idx (int)
constexpr size_t OF_AV    = OF_AIP  + (size_t)16*Nn;  // a vector (sign-parity encoded)
constexpr size_t OF_BV    = OF_AV   + LDKc;           // b vector (sign-parity encoded)
constexpr size_t OF_RINV  = OF_BV   + LDKc;           // 1/rowsum (positive, plain)
constexpr size_t OF_IDX0  = OF_RINV + LDKc;           // int
constexpr size_t OF_MAX0  = OF_IDX0 + Nn;
constexpr size_t OF_IDX1  = OF_MAX0 + Nn;             // int
constexpr size_t OF_ATTN  = OF_IDX1 + Nn;
constexpr size_t OF_PART  = OF_ATTN;                  // zfeat partials alias attn (dead)
constexpr size_t OF_PROBA = OF_ATTN + (size_t)Nn*Nn;
constexpr size_t OF_PROBB = OF_PROBA+ (size_t)Nn*Nn;
// K/KT alias attn/partials/probA region (dead before K is built)
constexpr size_t OF_K     = OF_ATTN;
constexpr size_t OF_KT    = OF_K + (size_t)Mm*LDKc;

// ---------- agent-scope (coherence-point) access helpers ----------
__device__ __forceinline__ float aloadf(const float* p) {
  return __hip_atomic_load((float*)p, __ATOMIC_RELAXED, __HIP_MEMORY_SCOPE_AGENT);
}
__device__ __forceinline__ void astoref(float* p, float v) {
  __hip_atomic_store(p, v, __ATOMIC_RELAXED, __HIP_MEMORY_SCOPE_AGENT);
}

// Poll the 17 entries this lane needs (l+64q, q<16, plus [1024]) until all carry the
// expected sign parity (neg=1 -> negative means ready). The poll IS the data read:
// one MALL visibility cycle per half-step, no flags, no grid barrier.
__device__ __forceinline__ void pollvec(const float* __restrict__ vec, int neg,
                                        float* v, int l) {
  for (;;) {
    bool ok = true;
#pragma unroll
    for (int q = 0; q < 16; ++q) {
      v[q] = aloadf(&vec[l + 64 * q]);
      ok &= neg ? (v[q] < 0.0f) : (v[q] > 0.0f);
    }
    v[16] = aloadf(&vec[1024]);
    ok &= neg ? (v[16] < 0.0f) : (v[16] > 0.0f);
    if (__all((int)ok)) return;
    __builtin_amdgcn_s_sleep(2);
  }
}

// mdesc = Wp @ desc + bp ; also writes transpose. grid (4, 64)
__global__ __launch_bounds__(TPB) void k_mdesc(const float* __restrict__ Wp,
                                               const float* __restrict__ bp,
                                               const float* __restrict__ desc,
                                               float* __restrict__ md,
                                               float* __restrict__ mdT) {
  int j = blockIdx.x * TPB + threadIdx.x;
  int d0 = blockIdx.y * 4;
  float acc[4] = {0.f, 0.f, 0.f, 0.f};
  for (int k = 0; k < Dd; ++k) {
    float v = desc[(size_t)k * Nn + j];
#pragma unroll
    for (int r = 0; r < 4; ++r) acc[r] += Wp[(size_t)(d0 + r) * Dd + k] * v;
  }
#pragma unroll
  for (int r = 0; r < 4; ++r) {
    acc[r] += bp[d0 + r];
    md[(size_t)(d0 + r) * Nn + j] = acc[r];
  }
  *(float4*)&mdT[(size_t)j * Dd + d0] = make_float4(acc[0], acc[1], acc[2], acc[3]);
}

// hA[n,o] / hBt[o,n]. grid (4,64,2)
__global__ __launch_bounds__(TPB) void k_h(const float* __restrict__ W1,
                                           const float* __restrict__ md0,
                                           const float* __restrict__ md1,
                                           float* __restrict__ hA,
                                           float* __restrict__ hBt) {
  int j = blockIdx.x * TPB + threadIdx.x;
  int o = blockIdx.y;
  int which = blockIdx.z;
  const float* md = which ? md1 : md0;
  const float* w = W1 + (size_t)o * 512 + which * 256;
  float acc = 0.f;
  for (int d = 0; d < Dd; ++d) acc += md[(size_t)d * Nn + j] * w[d];
  if (which == 0) hA[(size_t)j * 64 + o] = acc;
  else            hBt[(size_t)o * Nn + j] = acc;
}

// attn[i,j] = b2 + sum_o W2[o]*relu(hA[i,o]+hBt[o,j]+b1[o]). grid (4,256)
__global__ __launch_bounds__(TPB) void k_attn(const float* __restrict__ hA,
                                              const float* __restrict__ hBt,
                                              const float* __restrict__ W2,
                                              const float* __restrict__ b1,
                                              const float* __restrict__ b2,
                                              float* __restrict__ attn) {
  int j = blockIdx.x * TPB + threadIdx.x;
  int i0 = blockIdx.y * 4;
  float bias = b2[0];
  float acc[4] = {bias, bias, bias, bias};
  for (int o = 0; o < 64; ++o) {
    float hb = hBt[(size_t)o * Nn + j] + b1[o];
    float w = W2[o];
#pragma unroll
    for (int r = 0; r < 4; ++r) {
      float t = hA[(size_t)(i0 + r) * 64 + o] + hb;
      acc[r] += w * fmaxf(t, 0.f);
    }
  }
#pragma unroll
  for (int r = 0; r < 4; ++r) attn[(size_t)(i0 + r) * Nn + j] = acc[r];
}

// per-row softmax stats. grid 1024
__global__ __launch_bounds__(TPB) void k_rowstats(const float* __restrict__ attn,
                                                  float* __restrict__ rowM,
                                                  float* __restrict__ rowS) {
  int i = blockIdx.x, t = threadIdx.x;
  const float* row = attn + (size_t)i * Nn;
  float m = -INFINITY;
  for (int q = 0; q < 4; ++q) m = fmaxf(m, row[t + q * TPB]);
  __shared__ float red[TPB];
  red[t] = m; __syncthreads();
  for (int s = TPB / 2; s > 0; s >>= 1) {
    if (t < s) red[t] = fmaxf(red[t], red[t + s]);
    __syncthreads();
  }
  m = red[0]; __syncthreads();
  float ssum = 0.f;
  for (int q = 0; q < 4; ++q) ssum += expf(row[t + q * TPB] - m);
  red[t] = ssum; __syncthreads();
  for (int s = TPB / 2; s > 0; s >>= 1) {
    if (t < s) red[t] += red[t + s];
    __syncthreads();
  }
  if (t == 0) { rowM[i] = m; rowS[i] = red[0]; }
}

// column softmax stats, chunked over i. grid (4,16) then combine grid 4
__global__ __launch_bounds__(TPB) void k_colpart(const float* __restrict__ attn,
                                                 float* __restrict__ cmp,
                                                 float* __restrict__ csp) {
  int j = blockIdx.x * TPB + threadIdx.x;
  int c = blockIdx.y, i0 = c * 64;
  float m = -INFINITY;
  for (int q = 0; q < 64; ++q) m = fmaxf(m, attn[(size_t)(i0 + q) * Nn + j]);
  float s = 0.f;
  for (int q = 0; q < 64; ++q) s += expf(attn[(size_t)(i0 + q) * Nn + j] - m);
  cmp[(size_t)c * Nn + j] = m;
  csp[(size_t)c * Nn + j] = s;
}

__global__ __launch_bounds__(TPB) void k_colcomb(const float* __restrict__ cmp,
                                                 const float* __restrict__ csp,
                                                 float* __restrict__ colM,
                                                 float* __restrict__ colS) {
  int j = blockIdx.x * TPB + threadIdx.x;
  float m = -INFINITY;
  for (int c = 0; c < 16; ++c) m = fmaxf(m, cmp[(size_t)c * Nn + j]);
  float s = 0.f;
  for (int c = 0; c < 16; ++c) s += csp[(size_t)c * Nn + j] * expf(cmp[(size_t)c * Nn + j] - m);
  colM[j] = m; colS[j] = s;
}

// probA/probB materialization. grid (4,1024)
__global__ __launch_bounds__(TPB) void k_prob(const float* __restrict__ attn,
                                              const float* __restrict__ rowM,
                                              const float* __restrict__ rowS,
                                              const float* __restrict__ colM,
                                              const float* __restrict__ colS,
                                              float* __restrict__ probA,
                                              float* __restrict__ probB) {
  int j = blockIdx.x * TPB + threadIdx.x;
  int i = blockIdx.y;
  float v = attn[(size_t)i * Nn + j];
  probA[(size_t)i * Nn + j] = expf(v - rowM[i]) / rowS[i];
  probB[(size_t)i * Nn + j] = expf(v - colM[j]) / colS[j];
}

// zfeat partials: grid (256, 2, 2): x->4-row group, y->j half, z->side
__global__ __launch_bounds__(TPB) void k_zfeat_part(const float* __restrict__ probA,
                                                    const float* __restrict__ probB,
                                                    const float* __restrict__ md0T,
                                                    const float* __restrict__ md1T,
                                                    float* __restrict__ part) {
  int d = threadIdx.x;
  int r0 = blockIdx.x * 4;
  int jc = blockIdx.y;
  int side = blockIdx.z;
  const float* mdT  = side ? md0T : md1T;
  const float* prob = side ? probB : probA;
  int j0 = jc * 512;
  float acc[4] = {0.f, 0.f, 0.f, 0.f};
  if (side == 0) {
    for (int j = j0; j < j0 + 512; ++j) {
      float mv = mdT[(size_t)j * Dd + d];
#pragma unroll
      for (int r = 0; r < 4; ++r) acc[r] += prob[(size_t)(r0 + r) * Nn + j] * mv;
    }
  } else {
    for (int i = j0; i < j0 + 512; ++i) {
      float mv = mdT[(size_t)i * Dd + d];
#pragma unroll
      for (int r = 0; r < 4; ++r) acc[r] += prob[(size_t)i * Nn + (r0 + r)] * mv;
    }
  }
  float* dst = part + ((size_t)(side * 2 + jc)) * ((size_t)Nn * Dd);
#pragma unroll
  for (int r = 0; r < 4; ++r) dst[(size_t)(r0 + r) * Dd + d] = acc[r];
}

// combine partials: zf = p0 + p1. grid 2048
__global__ __launch_bounds__(TPB) void k_zfeat_comb(const float* __restrict__ part,
                                                    float* __restrict__ zfA,
                                                    float* __restrict__ zfB) {
  int idx = blockIdx.x * TPB + threadIdx.x;
  const size_t n = (size_t)Nn * Dd;
  if (idx < (int)n) zfA[idx] = part[idx] + part[n + idx];
  else {
    size_t k = (size_t)idx - n;
    zfB[k] = part[2 * n + k] + part[3 * n + k];
  }
}

// transpose Wz1 (256x256) and Wz2 (64x256). grid 320
__global__ __launch_bounds__(TPB) void k_transposeW(const float* __restrict__ Wz1,
                                                    const float* __restrict__ Wz2,
                                                    float* __restrict__ Wz1T,
                                                    float* __restrict__ Wz2T) {
  int t = threadIdx.x, b = blockIdx.x;
  if (b < 256) Wz1T[(size_t)t * 256 + b] = Wz1[(size_t)b * 256 + t];
  else {
    int o = b - 256;
    Wz2T[(size_t)t * 64 + o] = Wz2[(size_t)o * 256 + t];
  }
}

// zmlp over rows of zfeatA / zfeatB. grid (1024,2)
__global__ __launch_bounds__(TPB) void k_zmlp(const float* __restrict__ zfA,
                                              const float* __restrict__ zfB,
                                              const float* __restrict__ Wz1T,
                                              const float* __restrict__ bz1,
                                              const float* __restrict__ Wz2T,
                                              const float* __restrict__ bz2,
                                              const float* __restrict__ Wz3,
                                              const float* __restrict__ bz3,
                                              float* __restrict__ zA,
                                              float* __restrict__ zB) {
  int i = blockIdx.x, t = threadIdx.x, which = blockIdx.y;
  const float* x = (which ? zfB : zfA) + (size_t)i * Dd;
  __shared__ float xs[Dd];
  __shared__ float h1[Dd];
  __shared__ float h2[64];
  xs[t] = x[t];
  __syncthreads();
  float acc = bz1[t];
  for (int k = 0; k < Dd; ++k) acc += Wz1T[(size_t)k * Dd + t] * xs[k];
  h1[t] = fmaxf(acc, 0.f);
  __syncthreads();
  if (t < 64) {
    float a2 = bz2[t];
    for (int k = 0; k < Dd; ++k) a2 += Wz2T[(size_t)k * 64 + t] * h1[k];
    h2[t] = fmaxf(a2, 0.f);
  }
  __syncthreads();
  if (t < 64) {
    float p = Wz3[t] * h2[t];
#pragma unroll
    for (int off = 32; off > 0; off >>= 1) p += __shfl_down(p, off);
    if (t == 0) (which ? zB : zA)[i] = p + bz3[0];
  }
}

// K[i,j] = exp(scores[i,j]) for i,j<1024, also KT. grid (4,256)
__global__ __launch_bounds__(TPB) void k_buildK(const float* __restrict__ md0T,
                                                const float* __restrict__ md1,
                                                float* __restrict__ K,
                                                float* __restrict__ KT) {
  int j = blockIdx.x * TPB + threadIdx.x;
  int i0 = blockIdx.y * 4;
  float acc[4] = {0.f, 0.f, 0.f, 0.f};
  for (int d = 0; d < Dd; ++d) {
    float mv = md1[(size_t)d * Nn + j];
#pragma unroll
    for (int r = 0; r < 4; ++r) acc[r] += md0T[(size_t)(i0 + r) * Dd + d] * mv;
  }
  float vr[4];
#pragma unroll
  for (int r = 0; r < 4; ++r) {
    vr[r] = expf(acc[r] * 0.0625f);
    K[(size_t)(i0 + r) * LDKc + j] = vr[r];
  }
  *(float4*)&KT[(size_t)j * LDKc + i0] = make_float4(vr[0], vr[1], vr[2], vr[3]);
}

// dustbin row/col of K and KT. grid 5
__global__ __launch_bounds__(TPB) void k_edgeK(const float* __restrict__ zA,
                                               const float* __restrict__ zB,
                                               float* __restrict__ K,
                                               float* __restrict__ KT) {
  int idx = blockIdx.x * TPB + threadIdx.x;
  if (idx >= Mm) return;
  const float E1 = 2.7182818284590452f;  // exp(alpha=1)
  float ka = (idx < Nn) ? expf(zA[idx]) : E1;  // K[idx][1024]
  float kb = (idx < Nn) ? expf(zB[idx]) : E1;  // K[1024][idx]
  K[(size_t)idx * LDKc + Nn] = ka;
  KT[(size_t)Nn * LDKc + idx] = ka;
  K[(size_t)Nn * LDKc + idx] = kb;
  KT[(size_t)idx * LDKc + Nn] = kb;
}

// Dataflow Sinkhorn: 1 wave = 1 row, K/KT rows in VGPRs, sign-parity sync, no barriers.
// grid 257 x 256 (4 waves/block; block 256 wave 0 owns dustbin row 1024).
// Iteration it writes a,b negated iff (it&1); a stale (2-half-step-old) value always has
// the opposite sign, and a producer cannot overwrite gen h before all consumers read it
// (its next write transitively depends on their outputs).
__global__ __launch_bounds__(TPB) void k_sink_flow(
    const float* __restrict__ K, const float* __restrict__ KT,
    float* __restrict__ av, float* __restrict__ bv, float* __restrict__ rinv) {
  const int bid = blockIdx.x;
  const int t = threadIdx.x;
  const int w = t >> 6, l = t & 63;
  int row;
  if (bid < 256) row = bid * 4 + w;
  else { if (w > 0) return; row = 1024; }
  const float mu = (row < Nn) ? (1.0f / 2048.0f) : 0.5f;
  const float* kp = K + (size_t)row * LDKc;
  const float* tp = KT + (size_t)row * LDKc;
  float kr[16], tr[16];
#pragma unroll
  for (int q = 0; q < 16; ++q) { kr[q] = kp[l + 64 * q]; tr[q] = tp[l + 64 * q]; }
  const float k16 = (l == 0) ? kp[1024] : 0.0f;
  const float t16 = (l == 0) ? tp[1024] : 0.0f;

  float v[17];

  // it=0 a-phase: b == 1 implicitly; write a with sign +
  {
    float acc = k16;
#pragma unroll
    for (int q = 0; q < 16; ++q) acc += kr[q];
#pragma unroll
    for (int off = 32; off > 0; off >>= 1) acc += __shfl_xor(acc, off);
    if (l == 0) astoref(&av[row], mu / acc);
  }

  for (int it = 0; it < SINK_ITERS; ++it) {
    const int sout = it & 1;  // 1 -> this iteration's writes are negated
    // ---- b-phase: b = nu / (KT a); a carries sign sout ----
    {
      pollvec(av, sout, v, l);
      float acc = t16 * fabsf(v[16]);
#pragma unroll
      for (int q = 0; q < 16; ++q) acc += tr[q] * fabsf(v[q]);
#pragma unroll
      for (int off = 32; off > 0; off >>= 1) acc += __shfl_xor(acc, off);
      if (l == 0) { float r = mu / acc; astoref(&bv[row], sout ? -r : r); }
    }
    // ---- a-phase of it+1: reads b (sign sout), writes a with sign (it+1)&1 ----
    if (it + 1 < SINK_ITERS) {
      const int snew = (it + 1) & 1;
      pollvec(bv, sout, v, l);
      float acc = k16 * fabsf(v[16]);
#pragma unroll
      for (int q = 0; q < 16; ++q) acc += kr[q] * fabsf(v[q]);
#pragma unroll
      for (int off = 32; off > 0; off >>= 1) acc += __shfl_xor(acc, off);
      if (l == 0) { float r = mu / acc; astoref(&av[row], snew ? -r : r); }
    }
  }

  // final: rinv = 1/(K·|b|); last b written at it=99 -> negative parity
  {
    pollvec(bv, 1, v, l);
    float acc = k16 * fabsf(v[16]);
#pragma unroll
    for (int q = 0; q < 16; ++q) acc += kr[q] * fabsf(v[q]);
#pragma unroll
    for (int off = 32; off > 0; off >>= 1) acc += __shfl_xor(acc, off);
    if (l == 0) rinv[row] = 1.0f / acc;  // plain store; kernel boundary orders it
  }
}

// S[i,j] = K[i,j]*|b[j]|*rinv[i]. grid (5,1025)
__global__ __launch_bounds__(TPB) void k_S(const float* __restrict__ K,
                                           const float* __restrict__ bvec,
                                           const float* __restrict__ rinv,
                                           float* __restrict__ Sout) {
  int j = blockIdx.x * TPB + threadIdx.x;
  int i = blockIdx.y;
  if (j >= Mm) return;
  Sout[(size_t)i * Mm + j] = K[(size_t)i * LDKc + j] * fabsf(bvec[j]) * rinv[i];
}

// row argmax over inner part (j<1024). grid 1024
__global__ __launch_bounds__(TPB) void k_argmaxrow(const float* __restrict__ S,
                                                   int* __restrict__ idx0,
                                                   float* __restrict__ max0) {
  int i = blockIdx.x, t = threadIdx.x;
  const float* row = S + (size_t)i * Mm;
  float best = -INFINITY; int bj = 0;
  for (int q = 0; q < 4; ++q) {
    int j = t + q * TPB;
    float v = row[j];
    if (v > best) { best = v; bj = j; }
  }
  __shared__ float bvs[TPB];
  __shared__ int bis[TPB];
  bvs[t] = best; bis[t] = bj;
  __syncthreads();
  for (int s = TPB / 2; s > 0; s >>= 1) {
    if (t < s) {
      if (bvs[t + s] > bvs[t] || (bvs[t + s] == bvs[t] && bis[t + s] < bis[t])) {
        bvs[t] = bvs[t + s]; bis[t] = bis[t + s];
      }
    }
    __syncthreads();
  }
  if (t == 0) { idx0[i] = bis[0]; max0[i] = bvs[0]; }
}

// column argmax, chunked. grid (4,16) then combine grid 4
__global__ __launch_bounds__(TPB) void k_argcolpart(const float* __restrict__ S,
                                                    float* __restrict__ amp,
                                                    int* __restrict__ aip) {
  int j = blockIdx.x * TPB + threadIdx.x;
  int c = blockIdx.y, i0 = c * 64;
  float best = -INFINITY; int bi = i0;
  for (int q = 0; q < 64; ++q) {
    float v = S[(size_t)(i0 + q) * Mm + j];
    if (v > best) { best = v; bi = i0 + q; }
  }
  amp[(size_t)c * Nn + j] = best;
  aip[(size_t)c * Nn + j] = bi;
}

__global__ __launch_bounds__(TPB) void k_argcolcomb(const float* __restrict__ amp,
                                                    const int* __restrict__ aip,
                                                    int* __restrict__ idx1) {
  int j = blockIdx.x * TPB + threadIdx.x;
  float best = -INFINITY; int bi = 0;
  for (int c = 0; c < 16; ++c) {
    float v = amp[(size_t)c * Nn + j];
    if (v > best) { best = v; bi = aip[(size_t)c * Nn + j]; }
  }
  idx1[j] = bi;
}

// mutual matching + outputs. 1 block x 1024 threads
__global__ __launch_bounds__(1024) void k_match(const int* __restrict__ idx0,
                                                const float* __restrict__ max0,
                                                const int* __restrict__ idx1,
                                                float* __restrict__ out) {
  int t = threadIdx.x;
  __shared__ float ms0[Nn];
  __shared__ int v0[Nn];
  __shared__ int i0s[Nn];
  int j0 = idx0[t];
  bool mut0 = (idx1[j0] == t);
  float m0 = mut0 ? expf(max0[t]) : 0.f;
  bool val0 = mut0 && (m0 > 0.2f);
  ms0[t] = m0; v0[t] = val0 ? 1 : 0; i0s[t] = j0;
  out[t] = val0 ? (float)j0 : -1.f;           // indices0
  out[2048 + t] = m0;                          // mscores0
  __syncthreads();
  int i1 = idx1[t];
  bool mut1 = (i0s[i1] == t);
  float m1 = mut1 ? ms0[i1] : 0.f;
  bool val1 = mut1 && (v0[i1] != 0);
  out[1024 + t] = val1 ? (float)i1 : -1.f;     // indices1
  out[3072 + t] = m1;                          // mscores1
}

extern "C" void kernel_launch(void* const* d_in, const int* in_sizes, int n_in,
                              void* d_out, int out_size, void* d_ws, size_t ws_size,
                              hipStream_t stream) {
  (void)in_sizes; (void)n_in; (void)out_size; (void)ws_size;
  const float* desc0 = (const float*)d_in[0];
  const float* desc1 = (const float*)d_in[1];
  const float* Wp    = (const float*)d_in[2];
  const float* bp    = (const float*)d_in[3];
  const float* W1    = (const float*)d_in[4];
  const float* b1    = (const float*)d_in[5];
  const float* W2    = (const float*)d_in[6];
  const float* b2    = (const float*)d_in[7];
  const float* Wz1   = (const float*)d_in[8];
  const float* bz1   = (const float*)d_in[9];
  const float* Wz2   = (const float*)d_in[10];
  const float* bz2   = (const float*)d_in[11];
  const float* Wz3   = (const float*)d_in[12];
  const float* bz3   = (const float*)d_in[13];
  float* ws  = (float*)d_ws;
  float* out = (float*)d_out;
  dim3 blk(TPB);

  k_mdesc<<<dim3(4, 64), blk, 0, stream>>>(Wp, bp, desc0, ws + OF_MD0, ws + OF_MD0T);
  k_mdesc<<<dim3(4, 64), blk, 0, stream>>>(Wp, bp, desc1, ws + OF_MD1, ws + OF_MD1T);
  k_h<<<dim3(4, 64, 2), blk, 0, stream>>>(W1, ws + OF_MD0, ws + OF_MD1, ws + OF_HA, ws + OF_HBT);
  k_attn<<<dim3(4, 256), blk, 0, stream>>>(ws + OF_HA, ws + OF_HBT, W2, b1, b2, ws + OF_ATTN);
  k_rowstats<<<dim3(1024), blk, 0, stream>>>(ws + OF_ATTN, ws + OF_ROWM, ws + OF_ROWS);
  k_colpart<<<dim3(4, 16), blk, 0, stream>>>(ws + OF_ATTN, ws + OF_CMP, ws + OF_CSP);
  k_colcomb<<<dim3(4), blk, 0, stream>>>(ws + OF_CMP, ws + OF_CSP, ws + OF_COLM, ws + OF_COLS);
  k_prob<<<dim3(4, 1024), blk, 0, stream>>>(ws + OF_ATTN, ws + OF_ROWM, ws + OF_ROWS,
                                            ws + OF_COLM, ws + OF_COLS,
                                            ws + OF_PROBA, ws + OF_PROBB);
  // attn region is dead now; partials alias it
  k_zfeat_part<<<dim3(256, 2, 2), blk, 0, stream>>>(ws + OF_PROBA, ws + OF_PROBB,
                                                    ws + OF_MD0T, ws + OF_MD1T,
                                                    ws + OF_PART);
  k_zfeat_comb<<<dim3(2048), blk, 0, stream>>>(ws + OF_PART, ws + OF_ZFA, ws + OF_ZFB);
  k_transposeW<<<dim3(320), blk, 0, stream>>>(Wz1, Wz2, ws + OF_WZ1T, ws + OF_WZ2T);
  k_zmlp<<<dim3(1024, 2), blk, 0, stream>>>(ws + OF_ZFA, ws + OF_ZFB,
                                            ws + OF_WZ1T, bz1, ws + OF_WZ2T, bz2,
                                            Wz3, bz3, ws + OF_ZA, ws + OF_ZB);
  // ---- K build (clobbers partials/probA region; both dead) ----
  k_buildK<<<dim3(4, 256), blk, 0, stream>>>(ws + OF_MD0T, ws + OF_MD1,
                                             ws + OF_K, ws + OF_KT);
  k_edgeK<<<dim3(5), blk, 0, stream>>>(ws + OF_ZA, ws + OF_ZB, ws + OF_K, ws + OF_KT);
  // ---- dataflow Sinkhorn (no grid barriers) ----
  k_sink_flow<<<dim3(257), blk, 0, stream>>>(ws + OF_K, ws + OF_KT,
                                             ws + OF_AV, ws + OF_BV, ws + OF_RINV);
  // ---- epilogue ----
  float* Sout = out + 4096;
  k_S<<<dim3(5, 1025), blk, 0, stream>>>(ws + OF_K, ws + OF_BV, ws + OF_RINV, Sout);
  k_argmaxrow<<<dim3(1024), blk, 0, stream>>>(Sout, (int*)(ws + OF_IDX0), ws + OF_MAX0);
  k_argcolpart<<<dim3(4, 16), blk, 0, stream>>>(Sout, ws + OF_AMP, (int*)(ws + OF_AIP));
  k_argcolcomb<<<dim3(4), blk, 0, stream>>>(ws + OF_AMP, (const int*)(ws + OF_AIP),
                                            (int*)(ws + OF_IDX1));
  k_match<<<dim3(1), dim3(1024), 0, stream>>>((const int*)(ws + OF_IDX0), ws + OF_MAX0,
                                              (const int*)(ws + OF_IDX1), out);
}

// Round 6
// 956.134 us; speedup vs baseline: 1.5259x; 1.5259x over previous
//
#include <hip/hip_runtime.h>
#include <math.h>

#define TPB 256

constexpr int Dd = 256;
constexpr int Nn = 1024;
constexpr int Mm = 1025;      // Nn + 1 (with dustbin)
constexpr int LDKc = 1040;    // padded row stride for K / KT (16-float aligned)
constexpr int SINK_ITERS = 100;
constexpr int NB  = 64;       // flow blocks
constexpr int PT  = 1024;     // threads per flow block (16 waves, 1 wave = 1 row)

// ---- workspace layout (float offsets) ----
constexpr size_t OF_MD0   = 0;
constexpr size_t OF_MD1   = OF_MD0  + (size_t)Dd*Nn;
constexpr size_t OF_MD0T  = OF_MD1  + (size_t)Dd*Nn;
constexpr size_t OF_MD1T  = OF_MD0T + (size_t)Dd*Nn;
constexpr size_t OF_HA    = OF_MD1T + (size_t)Dd*Nn;
constexpr size_t OF_HBT   = OF_HA   + (size_t)Nn*64;
constexpr size_t OF_ZFA   = OF_HBT  + (size_t)Nn*64;
constexpr size_t OF_ZFB   = OF_ZFA  + (size_t)Nn*Dd;
constexpr size_t OF_WZ1T  = OF_ZFB  + (size_t)Nn*Dd;
constexpr size_t OF_WZ2T  = OF_WZ1T + (size_t)Dd*Dd;
constexpr size_t OF_ZA    = OF_WZ2T + (size_t)64*Dd;
constexpr size_t OF_ZB    = OF_ZA   + Nn;
constexpr size_t OF_ROWM  = OF_ZB   + Nn;
constexpr size_t OF_ROWS  = OF_ROWM + Nn;
constexpr size_t OF_CMP   = OF_ROWS + Nn;        // 16 x 1024 column partial max
constexpr size_t OF_CSP   = OF_CMP  + (size_t)16*Nn;
constexpr size_t OF_COLM  = OF_CSP  + (size_t)16*Nn;
constexpr size_t OF_COLS  = OF_COLM + Nn;
constexpr size_t OF_AV    = OF_COLS + Nn;             // a vector (sign-parity encoded)
constexpr size_t OF_BV    = OF_AV   + LDKc;           // b vector (sign-parity encoded)
constexpr size_t OF_RINV  = OF_BV   + LDKc;           // 1/rowsum; reset -1, ready > 0
constexpr size_t OF_IDX0  = OF_RINV + LDKc;           // int; reset -1, ready >= 0
constexpr size_t OF_MAX0  = OF_IDX0 + Nn;             // reset -1, ready > 0
constexpr size_t OF_IDX1  = OF_MAX0 + Nn;             // int; reset -1
constexpr size_t OF_ATTN  = OF_IDX1 + Nn;
constexpr size_t OF_PART  = OF_ATTN;                  // zfeat partials alias attn (dead)
constexpr size_t OF_PROBA = OF_ATTN + (size_t)Nn*Nn;
constexpr size_t OF_PROBB = OF_PROBA+ (size_t)Nn*Nn;
// K/KT alias attn/partials/probA region (dead before K is built)
constexpr size_t OF_K     = OF_ATTN;
constexpr size_t OF_KT    = OF_K + (size_t)Mm*LDKc;

// ---------- agent-scope (coherence-point) access helpers ----------
__device__ __forceinline__ float aloadf(const float* p) {
  return __hip_atomic_load((float*)p, __ATOMIC_RELAXED, __HIP_MEMORY_SCOPE_AGENT);
}
__device__ __forceinline__ int aloadi(const int* p) {
  return __hip_atomic_load((int*)p, __ATOMIC_RELAXED, __HIP_MEMORY_SCOPE_AGENT);
}
__device__ __forceinline__ void astoref(float* p, float v) {
  __hip_atomic_store(p, v, __ATOMIC_RELAXED, __HIP_MEMORY_SCOPE_AGENT);
}
__device__ __forceinline__ void astorei(int* p, int v) {
  __hip_atomic_store(p, v, __ATOMIC_RELAXED, __HIP_MEMORY_SCOPE_AGENT);
}

// one-entry parity poll: the poll IS the data read
__device__ __forceinline__ float pollsgn(const float* p, int neg) {
  for (;;) {
    float v = aloadf(p);
    if (neg ? (v < 0.0f) : (v > 0.0f)) return v;
    __builtin_amdgcn_s_sleep(1);
  }
}
__device__ __forceinline__ float pollp(const float* p) {   // ready: >= 0 (reset -1)
  for (;;) {
    float v = aloadf(p);
    if (v >= 0.0f) return v;
    __builtin_amdgcn_s_sleep(1);
  }
}
__device__ __forceinline__ int polli(const int* p) {       // ready: >= 0 (reset -1)
  for (;;) {
    int v = aloadi(p);
    if (v >= 0) return v;
    __builtin_amdgcn_s_sleep(1);
  }
}

// mdesc = Wp @ desc + bp ; also writes transpose. grid (4, 64)
__global__ __launch_bounds__(TPB) void k_mdesc(const float* __restrict__ Wp,
                                               const float* __restrict__ bp,
                                               const float* __restrict__ desc,
                                               float* __restrict__ md,
                                               float* __restrict__ mdT) {
  int j = blockIdx.x * TPB + threadIdx.x;
  int d0 = blockIdx.y * 4;
  float acc[4] = {0.f, 0.f, 0.f, 0.f};
  for (int k = 0; k < Dd; ++k) {
    float v = desc[(size_t)k * Nn + j];
#pragma unroll
    for (int r = 0; r < 4; ++r) acc[r] += Wp[(size_t)(d0 + r) * Dd + k] * v;
  }
#pragma unroll
  for (int r = 0; r < 4; ++r) {
    acc[r] += bp[d0 + r];
    md[(size_t)(d0 + r) * Nn + j] = acc[r];
  }
  *(float4*)&mdT[(size_t)j * Dd + d0] = make_float4(acc[0], acc[1], acc[2], acc[3]);
}

// hA[n,o] / hBt[o,n]. grid (4,64,2)
__global__ __launch_bounds__(TPB) void k_h(const float* __restrict__ W1,
                                           const float* __restrict__ md0,
                                           const float* __restrict__ md1,
                                           float* __restrict__ hA,
                                           float* __restrict__ hBt) {
  int j = blockIdx.x * TPB + threadIdx.x;
  int o = blockIdx.y;
  int which = blockIdx.z;
  const float* md = which ? md1 : md0;
  const float* w = W1 + (size_t)o * 512 + which * 256;
  float acc = 0.f;
  for (int d = 0; d < Dd; ++d) acc += md[(size_t)d * Nn + j] * w[d];
  if (which == 0) hA[(size_t)j * 64 + o] = acc;
  else            hBt[(size_t)o * Nn + j] = acc;
}

// attn[i,j] = b2 + sum_o W2[o]*relu(hA[i,o]+hBt[o,j]+b1[o]). grid (4,256)
__global__ __launch_bounds__(TPB) void k_attn(const float* __restrict__ hA,
                                              const float* __restrict__ hBt,
                                              const float* __restrict__ W2,
                                              const float* __restrict__ b1,
                                              const float* __restrict__ b2,
                                              float* __restrict__ attn) {
  int j = blockIdx.x * TPB + threadIdx.x;
  int i0 = blockIdx.y * 4;
  float bias = b2[0];
  float acc[4] = {bias, bias, bias, bias};
  for (int o = 0; o < 64; ++o) {
    float hb = hBt[(size_t)o * Nn + j] + b1[o];
    float w = W2[o];
#pragma unroll
    for (int r = 0; r < 4; ++r) {
      float t = hA[(size_t)(i0 + r) * 64 + o] + hb;
      acc[r] += w * fmaxf(t, 0.f);
    }
  }
#pragma unroll
  for (int r = 0; r < 4; ++r) attn[(size_t)(i0 + r) * Nn + j] = acc[r];
}

// per-row softmax stats. grid 1024
__global__ __launch_bounds__(TPB) void k_rowstats(const float* __restrict__ attn,
                                                  float* __restrict__ rowM,
                                                  float* __restrict__ rowS) {
  int i = blockIdx.x, t = threadIdx.x;
  const float* row = attn + (size_t)i * Nn;
  float m = -INFINITY;
  for (int q = 0; q < 4; ++q) m = fmaxf(m, row[t + q * TPB]);
  __shared__ float red[TPB];
  red[t] = m; __syncthreads();
  for (int s = TPB / 2; s > 0; s >>= 1) {
    if (t < s) red[t] = fmaxf(red[t], red[t + s]);
    __syncthreads();
  }
  m = red[0]; __syncthreads();
  float ssum = 0.f;
  for (int q = 0; q < 4; ++q) ssum += expf(row[t + q * TPB] - m);
  red[t] = ssum; __syncthreads();
  for (int s = TPB / 2; s > 0; s >>= 1) {
    if (t < s) red[t] += red[t + s];
    __syncthreads();
  }
  if (t == 0) { rowM[i] = m; rowS[i] = red[0]; }
}

// column softmax stats, chunked over i. grid (4,16) then combine grid 4
__global__ __launch_bounds__(TPB) void k_colpart(const float* __restrict__ attn,
                                                 float* __restrict__ cmp,
                                                 float* __restrict__ csp) {
  int j = blockIdx.x * TPB + threadIdx.x;
  int c = blockIdx.y, i0 = c * 64;
  float m = -INFINITY;
  for (int q = 0; q < 64; ++q) m = fmaxf(m, attn[(size_t)(i0 + q) * Nn + j]);
  float s = 0.f;
  for (int q = 0; q < 64; ++q) s += expf(attn[(size_t)(i0 + q) * Nn + j] - m);
  cmp[(size_t)c * Nn + j] = m;
  csp[(size_t)c * Nn + j] = s;
}

__global__ __launch_bounds__(TPB) void k_colcomb(const float* __restrict__ cmp,
                                                 const float* __restrict__ csp,
                                                 float* __restrict__ colM,
                                                 float* __restrict__ colS) {
  int j = blockIdx.x * TPB + threadIdx.x;
  float m = -INFINITY;
  for (int c = 0; c < 16; ++c) m = fmaxf(m, cmp[(size_t)c * Nn + j]);
  float s = 0.f;
  for (int c = 0; c < 16; ++c) s += csp[(size_t)c * Nn + j] * expf(cmp[(size_t)c * Nn + j] - m);
  colM[j] = m; colS[j] = s;
}

// probA/probB materialization. grid (4,1024)
__global__ __launch_bounds__(TPB) void k_prob(const float* __restrict__ attn,
                                              const float* __restrict__ rowM,
                                              const float* __restrict__ rowS,
                                              const float* __restrict__ colM,
                                              const float* __restrict__ colS,
                                              float* __restrict__ probA,
                                              float* __restrict__ probB) {
  int j = blockIdx.x * TPB + threadIdx.x;
  int i = blockIdx.y;
  float v = attn[(size_t)i * Nn + j];
  probA[(size_t)i * Nn + j] = expf(v - rowM[i]) / rowS[i];
  probB[(size_t)i * Nn + j] = expf(v - colM[j]) / colS[j];
}

// zfeat partials: grid (256, 2, 2): x->4-row group, y->j half, z->side
__global__ __launch_bounds__(TPB) void k_zfeat_part(const float* __restrict__ probA,
                                                    const float* __restrict__ probB,
                                                    const float* __restrict__ md0T,
                                                    const float* __restrict__ md1T,
                                                    float* __restrict__ part) {
  int d = threadIdx.x;
  int r0 = blockIdx.x * 4;
  int jc = blockIdx.y;
  int side = blockIdx.z;
  const float* mdT  = side ? md0T : md1T;
  const float* prob = side ? probB : probA;
  int j0 = jc * 512;
  float acc[4] = {0.f, 0.f, 0.f, 0.f};
  if (side == 0) {
    for (int j = j0; j < j0 + 512; ++j) {
      float mv = mdT[(size_t)j * Dd + d];
#pragma unroll
      for (int r = 0; r < 4; ++r) acc[r] += prob[(size_t)(r0 + r) * Nn + j] * mv;
    }
  } else {
    for (int i = j0; i < j0 + 512; ++i) {
      float mv = mdT[(size_t)i * Dd + d];
#pragma unroll
      for (int r = 0; r < 4; ++r) acc[r] += prob[(size_t)i * Nn + (r0 + r)] * mv;
    }
  }
  float* dst = part + ((size_t)(side * 2 + jc)) * ((size_t)Nn * Dd);
#pragma unroll
  for (int r = 0; r < 4; ++r) dst[(size_t)(r0 + r) * Dd + d] = acc[r];
}

// combine partials: zf = p0 + p1. grid 2048
__global__ __launch_bounds__(TPB) void k_zfeat_comb(const float* __restrict__ part,
                                                    float* __restrict__ zfA,
                                                    float* __restrict__ zfB) {
  int idx = blockIdx.x * TPB + threadIdx.x;
  const size_t n = (size_t)Nn * Dd;
  if (idx < (int)n) zfA[idx] = part[idx] + part[n + idx];
  else {
    size_t k = (size_t)idx - n;
    zfB[k] = part[2 * n + k] + part[3 * n + k];
  }
}

// transpose Wz1 (256x256) and Wz2 (64x256). grid 320
__global__ __launch_bounds__(TPB) void k_transposeW(const float* __restrict__ Wz1,
                                                    const float* __restrict__ Wz2,
                                                    float* __restrict__ Wz1T,
                                                    float* __restrict__ Wz2T) {
  int t = threadIdx.x, b = blockIdx.x;
  if (b < 256) Wz1T[(size_t)t * 256 + b] = Wz1[(size_t)b * 256 + t];
  else {
    int o = b - 256;
    Wz2T[(size_t)t * 64 + o] = Wz2[(size_t)o * 256 + t];
  }
}

// zmlp over rows of zfeatA / zfeatB. grid (1024,2)
__global__ __launch_bounds__(TPB) void k_zmlp(const float* __restrict__ zfA,
                                              const float* __restrict__ zfB,
                                              const float* __restrict__ Wz1T,
                                              const float* __restrict__ bz1,
                                              const float* __restrict__ Wz2T,
                                              const float* __restrict__ bz2,
                                              const float* __restrict__ Wz3,
                                              const float* __restrict__ bz3,
                                              float* __restrict__ zA,
                                              float* __restrict__ zB) {
  int i = blockIdx.x, t = threadIdx.x, which = blockIdx.y;
  const float* x = (which ? zfB : zfA) + (size_t)i * Dd;
  __shared__ float xs[Dd];
  __shared__ float h1[Dd];
  __shared__ float h2[64];
  xs[t] = x[t];
  __syncthreads();
  float acc = bz1[t];
  for (int k = 0; k < Dd; ++k) acc += Wz1T[(size_t)k * Dd + t] * xs[k];
  h1[t] = fmaxf(acc, 0.f);
  __syncthreads();
  if (t < 64) {
    float a2 = bz2[t];
    for (int k = 0; k < Dd; ++k) a2 += Wz2T[(size_t)k * 64 + t] * h1[k];
    h2[t] = fmaxf(a2, 0.f);
  }
  __syncthreads();
  if (t < 64) {
    float p = Wz3[t] * h2[t];
#pragma unroll
    for (int off = 32; off > 0; off >>= 1) p += __shfl_down(p, off);
    if (t == 0) (which ? zB : zA)[i] = p + bz3[0];
  }
}

// K[i,j] = exp(scores[i,j]) for i,j<1024, also KT. grid (4,256)
__global__ __launch_bounds__(TPB) void k_buildK(const float* __restrict__ md0T,
                                                const float* __restrict__ md1,
                                                float* __restrict__ K,
                                                float* __restrict__ KT) {
  int j = blockIdx.x * TPB + threadIdx.x;
  int i0 = blockIdx.y * 4;
  float acc[4] = {0.f, 0.f, 0.f, 0.f};
  for (int d = 0; d < Dd; ++d) {
    float mv = md1[(size_t)d * Nn + j];
#pragma unroll
    for (int r = 0; r < 4; ++r) acc[r] += md0T[(size_t)(i0 + r) * Dd + d] * mv;
  }
  float vr[4];
#pragma unroll
  for (int r = 0; r < 4; ++r) {
    vr[r] = expf(acc[r] * 0.0625f);
    K[(size_t)(i0 + r) * LDKc + j] = vr[r];
  }
  *(float4*)&KT[(size_t)j * LDKc + i0] = make_float4(vr[0], vr[1], vr[2], vr[3]);
}

// dustbin row/col of K and KT; reset all ready-flagged buffers. grid 5
__global__ __launch_bounds__(TPB) void k_edgeK(const float* __restrict__ zA,
                                               const float* __restrict__ zB,
                                               float* __restrict__ K,
                                               float* __restrict__ KT,
                                               float* __restrict__ rinvb,
                                               int* __restrict__ idx0,
                                               float* __restrict__ max0,
                                               int* __restrict__ idx1) {
  int idx = blockIdx.x * TPB + threadIdx.x;
  if (idx < Nn) { idx0[idx] = -1; idx1[idx] = -1; max0[idx] = -1.0f; }
  if (idx >= Mm) return;
  rinvb[idx] = -1.0f;
  const float E1 = 2.7182818284590452f;  // exp(alpha=1)
  float ka = (idx < Nn) ? expf(zA[idx]) : E1;  // K[idx][1024]
  float kb = (idx < Nn) ? expf(zB[idx]) : E1;  // K[1024][idx]
  K[(size_t)idx * LDKc + Nn] = ka;
  KT[(size_t)Nn * LDKc + idx] = ka;
  K[(size_t)Nn * LDKc + idx] = kb;
  KT[(size_t)idx * LDKc + Nn] = kb;
}

// Dataflow Sinkhorn + fused epilogue. grid NB x PT. Wave w of block b owns row
// b*16+w (K row in kr[], KT row in tr[], both in VGPRs). Sign-parity sync on the
// a/b vectors (gen g sign = g&1); ONE poll per thread per half-step, staged to LDS.
// Block 0 wave 0 additionally owns dustbin row 1024 (k2/t2 regs).
__global__ __launch_bounds__(PT) void k_sink_flow2(
    const float* __restrict__ K, const float* __restrict__ KT,
    float* __restrict__ av, float* __restrict__ bv, float* __restrict__ rinvb,
    int* __restrict__ idx0, float* __restrict__ max0, int* __restrict__ idx1,
    float* __restrict__ out) {
  const int bid = blockIdx.x;
  const int t = threadIdx.x;
  const int w = t >> 6, l = t & 63;
  const int row = bid * 16 + w;
  const bool extra = (bid == 0 && w == 0);
  const float MU = 1.0f / 2048.0f;

  const float* kp = K  + (size_t)row * LDKc;
  const float* tp = KT + (size_t)row * LDKc;
  float kr[16], tr[16];
#pragma unroll
  for (int q = 0; q < 16; ++q) { kr[q] = kp[l + 64 * q]; tr[q] = tp[l + 64 * q]; }
  const float k16 = (l == 0) ? kp[1024] : 0.0f;
  const float t16 = (l == 0) ? tp[1024] : 0.0f;
  float k2[16], t2[16];
  float k216 = 0.0f, t216 = 0.0f;
#pragma unroll
  for (int q = 0; q < 16; ++q) { k2[q] = 0.0f; t2[q] = 0.0f; }
  if (extra) {
    const float* kp2 = K  + (size_t)Nn * LDKc;
    const float* tp2 = KT + (size_t)Nn * LDKc;
#pragma unroll
    for (int q = 0; q < 16; ++q) { k2[q] = kp2[l + 64 * q]; t2[q] = tp2[l + 64 * q]; }
    if (l == 0) { k216 = kp2[1024]; t216 = tp2[1024]; }
  }

  __shared__ float xsA[LDKc];   // staged |a|
  __shared__ float xsB[LDKc];   // staged |b|
  __shared__ float rsv[LDKc];   // staged rinv
  __shared__ int   i0s[Nn], i1s[Nn], v0s[Nn];
  __shared__ float msg[Nn];

  // ---- a gen0 = mu / (K · 1) (no poll) ----
  {
    float acc = k16;
#pragma unroll
    for (int q = 0; q < 16; ++q) acc += kr[q];
#pragma unroll
    for (int off = 32; off > 0; off >>= 1) acc += __shfl_xor(acc, off);
    if (l == 0) astoref(&av[row], MU / acc);
    if (extra) {
      float a2 = k216;
#pragma unroll
      for (int q = 0; q < 16; ++q) a2 += k2[q];
#pragma unroll
      for (int off = 32; off > 0; off >>= 1) a2 += __shfl_xor(a2, off);
      if (l == 0) astoref(&av[1024], 0.5f / a2);
    }
  }

  for (int it = 0; it < SINK_ITERS; ++it) {
    const int sg = it & 1;
    // stage |a gen it| (one poll per thread)
    xsA[t] = fabsf(pollsgn(&av[t], sg));
    if (t == 0) xsA[1024] = fabsf(pollsgn(&av[1024], sg));
    __syncthreads();
    // b gen it = nu / (KT a)
    {
      float acc = t16 * xsA[1024];
#pragma unroll
      for (int q = 0; q < 16; ++q) acc += tr[q] * xsA[l + 64 * q];
#pragma unroll
      for (int off = 32; off > 0; off >>= 1) acc += __shfl_xor(acc, off);
      if (l == 0) { float r = MU / acc; astoref(&bv[row], sg ? -r : r); }
      if (extra) {
        float a2 = t216 * xsA[1024];
#pragma unroll
        for (int q = 0; q < 16; ++q) a2 += t2[q] * xsA[l + 64 * q];
#pragma unroll
        for (int off = 32; off > 0; off >>= 1) a2 += __shfl_xor(a2, off);
        if (l == 0) { float r = 0.5f / a2; astoref(&bv[1024], sg ? -r : r); }
      }
    }
    // stage |b gen it|
    xsB[t] = fabsf(pollsgn(&bv[t], sg));
    if (t == 0) xsB[1024] = fabsf(pollsgn(&bv[1024], sg));
    __syncthreads();
    // a gen it+1 = mu / (K b)
    if (it + 1 < SINK_ITERS) {
      const int sn = (it + 1) & 1;
      float acc = k16 * xsB[1024];
#pragma unroll
      for (int q = 0; q < 16; ++q) acc += kr[q] * xsB[l + 64 * q];
#pragma unroll
      for (int off = 32; off > 0; off >>= 1) acc += __shfl_xor(acc, off);
      if (l == 0) { float r = MU / acc; astoref(&av[row], sn ? -r : r); }
      if (extra) {
        float a2 = k216 * xsB[1024];
#pragma unroll
        for (int q = 0; q < 16; ++q) a2 += k2[q] * xsB[l + 64 * q];
#pragma unroll
        for (int off = 32; off > 0; off >>= 1) a2 += __shfl_xor(a2, off);
        if (l == 0) { float r = 0.5f / a2; astoref(&av[1024], sn ? -r : r); }
      }
    }
  }

  // ---- xsB holds |b final|: rinv = 1/(K·b) (ready flag: > 0, reset -1) ----
  {
    float acc = k16 * xsB[1024];
#pragma unroll
    for (int q = 0; q < 16; ++q) acc += kr[q] * xsB[l + 64 * q];
#pragma unroll
    for (int off = 32; off > 0; off >>= 1) acc += __shfl_xor(acc, off);
    if (l == 0) astoref(&rinvb[row], 1.0f / acc);
    if (extra) {
      float a2 = k216 * xsB[1024];
#pragma unroll
      for (int q = 0; q < 16; ++q) a2 += k2[q] * xsB[l + 64 * q];
#pragma unroll
      for (int off = 32; off > 0; off >>= 1) a2 += __shfl_xor(a2, off);
      if (l == 0) astoref(&rinvb[1024], 1.0f / a2);
    }
  }
  // stage rinv
  rsv[t] = pollp(&rinvb[t]);
  if (t == 0) rsv[1024] = pollp(&rinvb[1024]);
  __syncthreads();

  // ---- S rows + row argmax + col argmax ----
  float* Sbase = out + 4096;
  {
    float ri = rsv[row];
    float* srow = Sbase + (size_t)row * Mm;
    float bm = -1.0f; int bj = 0;
#pragma unroll
    for (int q = 0; q < 16; ++q) {
      int j = l + 64 * q;
      float s = (kr[q] * xsB[j]) * ri;
      srow[j] = s;
      if (s > bm) { bm = s; bj = j; }
    }
    if (l == 0) srow[1024] = (k16 * xsB[1024]) * ri;
#pragma unroll
    for (int off = 32; off > 0; off >>= 1) {
      float om = __shfl_xor(bm, off);
      int oj = __shfl_xor(bj, off);
      if (om > bm || (om == bm && oj < bj)) { bm = om; bj = oj; }
    }
    if (l == 0) { astorei(&idx0[row], bj); astoref(&max0[row], bm); }
    // column argmax for column `row` (bitwise-identical fp expression to S entries)
    float bc = xsB[row];
    float cm = -1.0f; int ci = 0;
#pragma unroll
    for (int q = 0; q < 16; ++q) {
      int i = l + 64 * q;
      float v = (tr[q] * bc) * rsv[i];
      if (v > cm) { cm = v; ci = i; }
    }
#pragma unroll
    for (int off = 32; off > 0; off >>= 1) {
      float om = __shfl_xor(cm, off);
      int oi = __shfl_xor(ci, off);
      if (om > cm || (om == cm && oi < ci)) { cm = om; ci = oi; }
    }
    if (l == 0) astorei(&idx1[row], ci);
    if (extra) {  // S row 1024 (no argmax)
      float ri2 = rsv[1024];
      float* sr2 = Sbase + (size_t)Nn * Mm;
#pragma unroll
      for (int q = 0; q < 16; ++q) {
        int j = l + 64 * q;
        sr2[j] = (k2[q] * xsB[j]) * ri2;
      }
      if (l == 0) sr2[1024] = (k216 * xsB[1024]) * ri2;
    }
  }

  // ---- mutual matching (block 0 polls idx/max ready-flags) ----
  if (bid == 0) {
    int j0  = polli(&idx0[t]);
    int i1v = polli(&idx1[t]);
    float mr = pollp(&max0[t]);
    i0s[t] = j0; i1s[t] = i1v;
    __syncthreads();
    bool mut0 = (i1s[j0] == t);
    float m0 = mut0 ? expf(mr) : 0.0f;   // reference: mscores0 = exp(row max of S)
    bool val0 = mut0 && (m0 > 0.2f);
    msg[t] = m0; v0s[t] = val0 ? 1 : 0;
    out[t] = val0 ? (float)j0 : -1.0f;   // indices0
    out[2048 + t] = m0;                   // mscores0
    __syncthreads();
    bool mut1 = (i0s[i1v] == t);
    float m1 = mut1 ? msg[i1v] : 0.0f;
    bool val1 = mut1 && (v0s[i1v] != 0);
    out[1024 + t] = val1 ? (float)i1v : -1.0f;  // indices1
    out[3072 + t] = m1;                          // mscores1
  }
}

extern "C" void kernel_launch(void* const* d_in, const int* in_sizes, int n_in,
                              void* d_out, int out_size, void* d_ws, size_t ws_size,
                              hipStream_t stream) {
  (void)in_sizes; (void)n_in; (void)out_size; (void)ws_size;
  const float* desc0 = (const float*)d_in[0];
  const float* desc1 = (const float*)d_in[1];
  const float* Wp    = (const float*)d_in[2];
  const float* bp    = (const float*)d_in[3];
  const float* W1    = (const float*)d_in[4];
  const float* b1    = (const float*)d_in[5];
  const float* W2    = (const float*)d_in[6];
  const float* b2    = (const float*)d_in[7];
  const float* Wz1   = (const float*)d_in[8];
  const float* bz1   = (const float*)d_in[9];
  const float* Wz2   = (const float*)d_in[10];
  const float* bz2   = (const float*)d_in[11];
  const float* Wz3   = (const float*)d_in[12];
  const float* bz3   = (const float*)d_in[13];
  float* ws  = (float*)d_ws;
  float* out = (float*)d_out;
  dim3 blk(TPB);

  k_mdesc<<<dim3(4, 64), blk, 0, stream>>>(Wp, bp, desc0, ws + OF_MD0, ws + OF_MD0T);
  k_mdesc<<<dim3(4, 64), blk, 0, stream>>>(Wp, bp, desc1, ws + OF_MD1, ws + OF_MD1T);
  k_h<<<dim3(4, 64, 2), blk, 0, stream>>>(W1, ws + OF_MD0, ws + OF_MD1, ws + OF_HA, ws + OF_HBT);
  k_attn<<<dim3(4, 256), blk, 0, stream>>>(ws + OF_HA, ws + OF_HBT, W2, b1, b2, ws + OF_ATTN);
  k_rowstats<<<dim3(1024), blk, 0, stream>>>(ws + OF_ATTN, ws + OF_ROWM, ws + OF_ROWS);
  k_colpart<<<dim3(4, 16), blk, 0, stream>>>(ws + OF_ATTN, ws + OF_CMP, ws + OF_CSP);
  k_colcomb<<<dim3(4), blk, 0, stream>>>(ws + OF_CMP, ws + OF_CSP, ws + OF_COLM, ws + OF_COLS);
  k_prob<<<dim3(4, 1024), blk, 0, stream>>>(ws + OF_ATTN, ws + OF_ROWM, ws + OF_ROWS,
                                            ws + OF_COLM, ws + OF_COLS,
                                            ws + OF_PROBA, ws + OF_PROBB);
  // attn region is dead now; partials alias it
  k_zfeat_part<<<dim3(256, 2, 2), blk, 0, stream>>>(ws + OF_PROBA, ws + OF_PROBB,
                                                    ws + OF_MD0T, ws + OF_MD1T,
                                                    ws + OF_PART);
  k_zfeat_comb<<<dim3(2048), blk, 0, stream>>>(ws + OF_PART, ws + OF_ZFA, ws + OF_ZFB);
  k_transposeW<<<dim3(320), blk, 0, stream>>>(Wz1, Wz2, ws + OF_WZ1T, ws + OF_WZ2T);
  k_zmlp<<<dim3(1024, 2), blk, 0, stream>>>(ws + OF_ZFA, ws + OF_ZFB,
                                            ws + OF_WZ1T, bz1, ws + OF_WZ2T, bz2,
                                            Wz3, bz3, ws + OF_ZA, ws + OF_ZB);
  // ---- K build (clobbers partials/probA region; both dead) ----
  k_buildK<<<dim3(4, 256), blk, 0, stream>>>(ws + OF_MD0T, ws + OF_MD1,
                                             ws + OF_K, ws + OF_KT);
  k_edgeK<<<dim3(5), blk, 0, stream>>>(ws + OF_ZA, ws + OF_ZB, ws + OF_K, ws + OF_KT,
                                       ws + OF_RINV, (int*)(ws + OF_IDX0),
                                       ws + OF_MAX0, (int*)(ws + OF_IDX1));
  // ---- dataflow Sinkhorn + fused epilogue ----
  k_sink_flow2<<<dim3(NB), dim3(PT), 0, stream>>>(
      ws + OF_K, ws + OF_KT, ws + OF_AV, ws + OF_BV, ws + OF_RINV,
      (int*)(ws + OF_IDX0), ws + OF_MAX0, (int*)(ws + OF_IDX1), out);
}

// Round 7
// 245.605 us; speedup vs baseline: 5.9401x; 3.8930x over previous
//
#include <hip/hip_runtime.h>
#include <math.h>

#define TPB 256

constexpr int Dd = 256;
constexpr int Nn = 1024;
constexpr int Mm = 1025;      // Nn + 1 (with dustbin)
constexpr int LDKc = 1040;    // padded row stride for K / KT (16-float aligned)
constexpr int SINK_ITERS = 100;
constexpr int NB  = 64;       // flow blocks
constexpr int PT  = 1024;     // threads per flow block (16 waves, 1 wave = 1 row)

// ---- workspace layout (float offsets) ----
constexpr size_t OF_MD0   = 0;
constexpr size_t OF_MD1   = OF_MD0  + (size_t)Dd*Nn;
constexpr size_t OF_MD0T  = OF_MD1  + (size_t)Dd*Nn;
constexpr size_t OF_MD1T  = OF_MD0T + (size_t)Dd*Nn;
constexpr size_t OF_HA    = OF_MD1T + (size_t)Dd*Nn;
constexpr size_t OF_HBT   = OF_HA   + (size_t)Nn*64;
constexpr size_t OF_ZFA   = OF_HBT  + (size_t)Nn*64;
constexpr size_t OF_ZFB   = OF_ZFA  + (size_t)Nn*Dd;
constexpr size_t OF_WZ1T  = OF_ZFB  + (size_t)Nn*Dd;
constexpr size_t OF_WZ2T  = OF_WZ1T + (size_t)Dd*Dd;
constexpr size_t OF_ZA    = OF_WZ2T + (size_t)64*Dd;
constexpr size_t OF_ZB    = OF_ZA   + Nn;
constexpr size_t OF_ROWM  = OF_ZB   + Nn;
constexpr size_t OF_ROWS  = OF_ROWM + Nn;
constexpr size_t OF_CMP   = OF_ROWS + Nn;        // 16 x 1024 column partial max
constexpr size_t OF_CSP   = OF_CMP  + (size_t)16*Nn;
constexpr size_t OF_COLM  = OF_CSP  + (size_t)16*Nn;
constexpr size_t OF_COLS  = OF_COLM + Nn;
constexpr size_t OF_AV    = OF_COLS + Nn;             // a vector (sign-parity encoded; reset 0)
constexpr size_t OF_BV    = OF_AV   + LDKc;           // b vector (sign-parity encoded; reset 0)
constexpr size_t OF_RINV  = OF_BV   + LDKc;           // 1/rowsum; reset -1, ready >= 0
constexpr size_t OF_IDX0  = OF_RINV + LDKc;           // int; reset -1, ready >= 0
constexpr size_t OF_MAX0  = OF_IDX0 + Nn;             // reset -1, ready >= 0
constexpr size_t OF_IDX1  = OF_MAX0 + Nn;             // int; reset -1
constexpr size_t OF_ATTN  = OF_IDX1 + Nn;
constexpr size_t OF_PART  = OF_ATTN;                  // zfeat partials alias attn (dead)
constexpr size_t OF_PROBA = OF_ATTN + (size_t)Nn*Nn;
constexpr size_t OF_PROBB = OF_PROBA+ (size_t)Nn*Nn;
// K/KT alias attn/partials/probA region (dead before K is built)
constexpr size_t OF_K     = OF_ATTN;
constexpr size_t OF_KT    = OF_K + (size_t)Mm*LDKc;

// ---------- agent-scope (coherence-point) access helpers ----------
__device__ __forceinline__ float aloadf(const float* p) {
  return __hip_atomic_load((float*)p, __ATOMIC_RELAXED, __HIP_MEMORY_SCOPE_AGENT);
}
__device__ __forceinline__ int aloadi(const int* p) {
  return __hip_atomic_load((int*)p, __ATOMIC_RELAXED, __HIP_MEMORY_SCOPE_AGENT);
}
__device__ __forceinline__ void astoref(float* p, float v) {
  __hip_atomic_store(p, v, __ATOMIC_RELAXED, __HIP_MEMORY_SCOPE_AGENT);
}
__device__ __forceinline__ void astorei(int* p, int v) {
  __hip_atomic_store(p, v, __ATOMIC_RELAXED, __HIP_MEMORY_SCOPE_AGENT);
}

// one-entry parity poll: the poll IS the data read (0 fails both tests -> "reset")
__device__ __forceinline__ float pollsgn(const float* p, int neg) {
  for (;;) {
    float v = aloadf(p);
    if (neg ? (v < 0.0f) : (v > 0.0f)) return v;
    __builtin_amdgcn_s_sleep(1);
  }
}
__device__ __forceinline__ float pollp(const float* p) {   // ready: >= 0 (reset -1)
  for (;;) {
    float v = aloadf(p);
    if (v >= 0.0f) return v;
    __builtin_amdgcn_s_sleep(1);
  }
}
__device__ __forceinline__ int polli(const int* p) {       // ready: >= 0 (reset -1)
  for (;;) {
    int v = aloadi(p);
    if (v >= 0) return v;
    __builtin_amdgcn_s_sleep(1);
  }
}

// mdesc = Wp @ desc + bp ; also writes transpose. grid (4, 64)
__global__ __launch_bounds__(TPB) void k_mdesc(const float* __restrict__ Wp,
                                               const float* __restrict__ bp,
                                               const float* __restrict__ desc,
                                               float* __restrict__ md,
                                               float* __restrict__ mdT) {
  int j = blockIdx.x * TPB + threadIdx.x;
  int d0 = blockIdx.y * 4;
  float acc[4] = {0.f, 0.f, 0.f, 0.f};
  for (int k = 0; k < Dd; ++k) {
    float v = desc[(size_t)k * Nn + j];
#pragma unroll
    for (int r = 0; r < 4; ++r) acc[r] += Wp[(size_t)(d0 + r) * Dd + k] * v;
  }
#pragma unroll
  for (int r = 0; r < 4; ++r) {
    acc[r] += bp[d0 + r];
    md[(size_t)(d0 + r) * Nn + j] = acc[r];
  }
  *(float4*)&mdT[(size_t)j * Dd + d0] = make_float4(acc[0], acc[1], acc[2], acc[3]);
}

// hA[n,o] / hBt[o,n]. grid (4,64,2)
__global__ __launch_bounds__(TPB) void k_h(const float* __restrict__ W1,
                                           const float* __restrict__ md0,
                                           const float* __restrict__ md1,
                                           float* __restrict__ hA,
                                           float* __restrict__ hBt) {
  int j = blockIdx.x * TPB + threadIdx.x;
  int o = blockIdx.y;
  int which = blockIdx.z;
  const float* md = which ? md1 : md0;
  const float* w = W1 + (size_t)o * 512 + which * 256;
  float acc = 0.f;
  for (int d = 0; d < Dd; ++d) acc += md[(size_t)d * Nn + j] * w[d];
  if (which == 0) hA[(size_t)j * 64 + o] = acc;
  else            hBt[(size_t)o * Nn + j] = acc;
}

// attn[i,j] = b2 + sum_o W2[o]*relu(hA[i,o]+hBt[o,j]+b1[o]). grid (4,256)
__global__ __launch_bounds__(TPB) void k_attn(const float* __restrict__ hA,
                                              const float* __restrict__ hBt,
                                              const float* __restrict__ W2,
                                              const float* __restrict__ b1,
                                              const float* __restrict__ b2,
                                              float* __restrict__ attn) {
  int j = blockIdx.x * TPB + threadIdx.x;
  int i0 = blockIdx.y * 4;
  float bias = b2[0];
  float acc[4] = {bias, bias, bias, bias};
  for (int o = 0; o < 64; ++o) {
    float hb = hBt[(size_t)o * Nn + j] + b1[o];
    float w = W2[o];
#pragma unroll
    for (int r = 0; r < 4; ++r) {
      float t = hA[(size_t)(i0 + r) * 64 + o] + hb;
      acc[r] += w * fmaxf(t, 0.f);
    }
  }
#pragma unroll
  for (int r = 0; r < 4; ++r) attn[(size_t)(i0 + r) * Nn + j] = acc[r];
}

// per-row softmax stats. grid 1024
__global__ __launch_bounds__(TPB) void k_rowstats(const float* __restrict__ attn,
                                                  float* __restrict__ rowM,
                                                  float* __restrict__ rowS) {
  int i = blockIdx.x, t = threadIdx.x;
  const float* row = attn + (size_t)i * Nn;
  float m = -INFINITY;
  for (int q = 0; q < 4; ++q) m = fmaxf(m, row[t + q * TPB]);
  __shared__ float red[TPB];
  red[t] = m; __syncthreads();
  for (int s = TPB / 2; s > 0; s >>= 1) {
    if (t < s) red[t] = fmaxf(red[t], red[t + s]);
    __syncthreads();
  }
  m = red[0]; __syncthreads();
  float ssum = 0.f;
  for (int q = 0; q < 4; ++q) ssum += expf(row[t + q * TPB] - m);
  red[t] = ssum; __syncthreads();
  for (int s = TPB / 2; s > 0; s >>= 1) {
    if (t < s) red[t] += red[t + s];
    __syncthreads();
  }
  if (t == 0) { rowM[i] = m; rowS[i] = red[0]; }
}

// column softmax stats, chunked over i. grid (4,16) then combine grid 4
__global__ __launch_bounds__(TPB) void k_colpart(const float* __restrict__ attn,
                                                 float* __restrict__ cmp,
                                                 float* __restrict__ csp) {
  int j = blockIdx.x * TPB + threadIdx.x;
  int c = blockIdx.y, i0 = c * 64;
  float m = -INFINITY;
  for (int q = 0; q < 64; ++q) m = fmaxf(m, attn[(size_t)(i0 + q) * Nn + j]);
  float s = 0.f;
  for (int q = 0; q < 64; ++q) s += expf(attn[(size_t)(i0 + q) * Nn + j] - m);
  cmp[(size_t)c * Nn + j] = m;
  csp[(size_t)c * Nn + j] = s;
}

__global__ __launch_bounds__(TPB) void k_colcomb(const float* __restrict__ cmp,
                                                 const float* __restrict__ csp,
                                                 float* __restrict__ colM,
                                                 float* __restrict__ colS) {
  int j = blockIdx.x * TPB + threadIdx.x;
  float m = -INFINITY;
  for (int c = 0; c < 16; ++c) m = fmaxf(m, cmp[(size_t)c * Nn + j]);
  float s = 0.f;
  for (int c = 0; c < 16; ++c) s += csp[(size_t)c * Nn + j] * expf(cmp[(size_t)c * Nn + j] - m);
  colM[j] = m; colS[j] = s;
}

// probA/probB materialization. grid (4,1024)
__global__ __launch_bounds__(TPB) void k_prob(const float* __restrict__ attn,
                                              const float* __restrict__ rowM,
                                              const float* __restrict__ rowS,
                                              const float* __restrict__ colM,
                                              const float* __restrict__ colS,
                                              float* __restrict__ probA,
                                              float* __restrict__ probB) {
  int j = blockIdx.x * TPB + threadIdx.x;
  int i = blockIdx.y;
  float v = attn[(size_t)i * Nn + j];
  probA[(size_t)i * Nn + j] = expf(v - rowM[i]) / rowS[i];
  probB[(size_t)i * Nn + j] = expf(v - colM[j]) / colS[j];
}

// zfeat partials: grid (256, 2, 2): x->4-row group, y->j half, z->side
__global__ __launch_bounds__(TPB) void k_zfeat_part(const float* __restrict__ probA,
                                                    const float* __restrict__ probB,
                                                    const float* __restrict__ md0T,
                                                    const float* __restrict__ md1T,
                                                    float* __restrict__ part) {
  int d = threadIdx.x;
  int r0 = blockIdx.x * 4;
  int jc = blockIdx.y;
  int side = blockIdx.z;
  const float* mdT  = side ? md0T : md1T;
  const float* prob = side ? probB : probA;
  int j0 = jc * 512;
  float acc[4] = {0.f, 0.f, 0.f, 0.f};
  if (side == 0) {
    for (int j = j0; j < j0 + 512; ++j) {
      float mv = mdT[(size_t)j * Dd + d];
#pragma unroll
      for (int r = 0; r < 4; ++r) acc[r] += prob[(size_t)(r0 + r) * Nn + j] * mv;
    }
  } else {
    for (int i = j0; i < j0 + 512; ++i) {
      float mv = mdT[(size_t)i * Dd + d];
#pragma unroll
      for (int r = 0; r < 4; ++r) acc[r] += prob[(size_t)i * Nn + (r0 + r)] * mv;
    }
  }
  float* dst = part + ((size_t)(side * 2 + jc)) * ((size_t)Nn * Dd);
#pragma unroll
  for (int r = 0; r < 4; ++r) dst[(size_t)(r0 + r) * Dd + d] = acc[r];
}

// combine partials: zf = p0 + p1. grid 2048
__global__ __launch_bounds__(TPB) void k_zfeat_comb(const float* __restrict__ part,
                                                    float* __restrict__ zfA,
                                                    float* __restrict__ zfB) {
  int idx = blockIdx.x * TPB + threadIdx.x;
  const size_t n = (size_t)Nn * Dd;
  if (idx < (int)n) zfA[idx] = part[idx] + part[n + idx];
  else {
    size_t k = (size_t)idx - n;
    zfB[k] = part[2 * n + k] + part[3 * n + k];
  }
}

// transpose Wz1 (256x256) and Wz2 (64x256). grid 320
__global__ __launch_bounds__(TPB) void k_transposeW(const float* __restrict__ Wz1,
                                                    const float* __restrict__ Wz2,
                                                    float* __restrict__ Wz1T,
                                                    float* __restrict__ Wz2T) {
  int t = threadIdx.x, b = blockIdx.x;
  if (b < 256) Wz1T[(size_t)t * 256 + b] = Wz1[(size_t)b * 256 + t];
  else {
    int o = b - 256;
    Wz2T[(size_t)t * 64 + o] = Wz2[(size_t)o * 256 + t];
  }
}

// zmlp over rows of zfeatA / zfeatB. grid (1024,2)
__global__ __launch_bounds__(TPB) void k_zmlp(const float* __restrict__ zfA,
                                              const float* __restrict__ zfB,
                                              const float* __restrict__ Wz1T,
                                              const float* __restrict__ bz1,
                                              const float* __restrict__ Wz2T,
                                              const float* __restrict__ bz2,
                                              const float* __restrict__ Wz3,
                                              const float* __restrict__ bz3,
                                              float* __restrict__ zA,
                                              float* __restrict__ zB) {
  int i = blockIdx.x, t = threadIdx.x, which = blockIdx.y;
  const float* x = (which ? zfB : zfA) + (size_t)i * Dd;
  __shared__ float xs[Dd];
  __shared__ float h1[Dd];
  __shared__ float h2[64];
  xs[t] = x[t];
  __syncthreads();
  float acc = bz1[t];
  for (int k = 0; k < Dd; ++k) acc += Wz1T[(size_t)k * Dd + t] * xs[k];
  h1[t] = fmaxf(acc, 0.f);
  __syncthreads();
  if (t < 64) {
    float a2 = bz2[t];
    for (int k = 0; k < Dd; ++k) a2 += Wz2T[(size_t)k * 64 + t] * h1[k];
    h2[t] = fmaxf(a2, 0.f);
  }
  __syncthreads();
  if (t < 64) {
    float p = Wz3[t] * h2[t];
#pragma unroll
    for (int off = 32; off > 0; off >>= 1) p += __shfl_down(p, off);
    if (t == 0) (which ? zB : zA)[i] = p + bz3[0];
  }
}

// K[i,j] = exp(scores[i,j]) for i,j<1024, also KT. grid (4,256)
__global__ __launch_bounds__(TPB) void k_buildK(const float* __restrict__ md0T,
                                                const float* __restrict__ md1,
                                                float* __restrict__ K,
                                                float* __restrict__ KT) {
  int j = blockIdx.x * TPB + threadIdx.x;
  int i0 = blockIdx.y * 4;
  float acc[4] = {0.f, 0.f, 0.f, 0.f};
  for (int d = 0; d < Dd; ++d) {
    float mv = md1[(size_t)d * Nn + j];
#pragma unroll
    for (int r = 0; r < 4; ++r) acc[r] += md0T[(size_t)(i0 + r) * Dd + d] * mv;
  }
  float vr[4];
#pragma unroll
  for (int r = 0; r < 4; ++r) {
    vr[r] = expf(acc[r] * 0.0625f);
    K[(size_t)(i0 + r) * LDKc + j] = vr[r];
  }
  *(float4*)&KT[(size_t)j * LDKc + i0] = make_float4(vr[0], vr[1], vr[2], vr[3]);
}

// dustbin row/col of K and KT; reset sync buffers (av/bv -> 0 kills stale parity
// across graph replays; rinv/idx/max -> -1 ready-flags). grid 5
__global__ __launch_bounds__(TPB) void k_edgeK(const float* __restrict__ zA,
                                               const float* __restrict__ zB,
                                               float* __restrict__ K,
                                               float* __restrict__ KT,
                                               float* __restrict__ av,
                                               float* __restrict__ bv,
                                               float* __restrict__ rinvb,
                                               int* __restrict__ idx0,
                                               float* __restrict__ max0,
                                               int* __restrict__ idx1) {
  int idx = blockIdx.x * TPB + threadIdx.x;
  if (idx < Nn) { idx0[idx] = -1; idx1[idx] = -1; max0[idx] = -1.0f; }
  if (idx >= Mm) return;
  av[idx] = 0.0f; bv[idx] = 0.0f; rinvb[idx] = -1.0f;
  const float E1 = 2.7182818284590452f;  // exp(alpha=1)
  float ka = (idx < Nn) ? expf(zA[idx]) : E1;  // K[idx][1024]
  float kb = (idx < Nn) ? expf(zB[idx]) : E1;  // K[1024][idx]
  K[(size_t)idx * LDKc + Nn] = ka;
  KT[(size_t)Nn * LDKc + idx] = ka;
  K[(size_t)Nn * LDKc + idx] = kb;
  KT[(size_t)idx * LDKc + Nn] = kb;
}

// Dataflow Sinkhorn + fused epilogue + EARLY EXIT on convergence.
// grid NB x PT. Wave w of block b owns row b*16+w (K row kr[], KT row tr[], in VGPRs).
// Sign-parity sync on a/b (gen g sign = g&1); ONE poll per thread per half-step.
// Every block stages the full b vector each iteration -> each block locally detects
// "b unchanged within rel tol" on IDENTICAL data -> all blocks break at the same
// iteration with no extra communication. Deterministic.
__global__ __launch_bounds__(PT) void k_sink_flow2(
    const float* __restrict__ K, const float* __restrict__ KT,
    float* __restrict__ av, float* __restrict__ bv, float* __restrict__ rinvb,
    int* __restrict__ idx0, float* __restrict__ max0, int* __restrict__ idx1,
    float* __restrict__ out) {
  const int bid = blockIdx.x;
  const int t = threadIdx.x;
  const int w = t >> 6, l = t & 63;
  const int row = bid * 16 + w;
  const bool extra = (bid == 0 && w == 0);
  const float MU = 1.0f / 2048.0f;
  const float TOL = 1e-6f;   // rel convergence tol on b (S error << absmax headroom)

  const float* kp = K  + (size_t)row * LDKc;
  const float* tp = KT + (size_t)row * LDKc;
  float kr[16], tr[16];
#pragma unroll
  for (int q = 0; q < 16; ++q) { kr[q] = kp[l + 64 * q]; tr[q] = tp[l + 64 * q]; }
  const float k16 = (l == 0) ? kp[1024] : 0.0f;
  const float t16 = (l == 0) ? tp[1024] : 0.0f;
  float k2[16], t2[16];
  float k216 = 0.0f, t216 = 0.0f;
#pragma unroll
  for (int q = 0; q < 16; ++q) { k2[q] = 0.0f; t2[q] = 0.0f; }
  if (extra) {
    const float* kp2 = K  + (size_t)Nn * LDKc;
    const float* tp2 = KT + (size_t)Nn * LDKc;
#pragma unroll
    for (int q = 0; q < 16; ++q) { k2[q] = kp2[l + 64 * q]; t2[q] = tp2[l + 64 * q]; }
    if (l == 0) { k216 = kp2[1024]; t216 = tp2[1024]; }
  }

  __shared__ float xsA[LDKc];   // staged |a|
  __shared__ float xsB[LDKc];   // staged |b|
  __shared__ float rsv[LDKc];   // staged rinv
  __shared__ int   i0s[Nn], i1s[Nn], v0s[Nn];
  __shared__ float msg[Nn];
  __shared__ int   chgflag;

  float prevB = -1.0f, prevB1024 = -1.0f;   // impossible values -> first compare = changed

  // ---- a gen0 = mu / (K · 1) (no poll) ----
  {
    float acc = k16;
#pragma unroll
    for (int q = 0; q < 16; ++q) acc += kr[q];
#pragma unroll
    for (int off = 32; off > 0; off >>= 1) acc += __shfl_xor(acc, off);
    if (l == 0) astoref(&av[row], MU / acc);
    if (extra) {
      float a2 = k216;
#pragma unroll
      for (int q = 0; q < 16; ++q) a2 += k2[q];
#pragma unroll
      for (int off = 32; off > 0; off >>= 1) a2 += __shfl_xor(a2, off);
      if (l == 0) astoref(&av[1024], 0.5f / a2);
    }
  }

  for (int it = 0; it < SINK_ITERS; ++it) {
    const int sg = it & 1;
    // stage |a gen it| (one poll per thread)
    xsA[t] = fabsf(pollsgn(&av[t], sg));
    if (t == 0) xsA[1024] = fabsf(pollsgn(&av[1024], sg));
    __syncthreads();                        // S1
    if (t == 0) chgflag = 0;                // safe: all threads read prev flag before S1
    // b gen it = nu / (KT a)
    {
      float acc = t16 * xsA[1024];
#pragma unroll
      for (int q = 0; q < 16; ++q) acc += tr[q] * xsA[l + 64 * q];
#pragma unroll
      for (int off = 32; off > 0; off >>= 1) acc += __shfl_xor(acc, off);
      if (l == 0) { float r = MU / acc; astoref(&bv[row], sg ? -r : r); }
      if (extra) {
        float a2 = t216 * xsA[1024];
#pragma unroll
        for (int q = 0; q < 16; ++q) a2 += t2[q] * xsA[l + 64 * q];
#pragma unroll
        for (int off = 32; off > 0; off >>= 1) a2 += __shfl_xor(a2, off);
        if (l == 0) { float r = 0.5f / a2; astoref(&bv[1024], sg ? -r : r); }
      }
    }
    // stage |b gen it| + convergence test vs previous iteration's b
    {
      float nb = fabsf(pollsgn(&bv[t], sg));
      xsB[t] = nb;
      bool ch = fabsf(nb - prevB) > TOL * nb;
      prevB = nb;
      if (t == 0) {
        float nb2 = fabsf(pollsgn(&bv[1024], sg));
        xsB[1024] = nb2;
        ch |= fabsf(nb2 - prevB1024) > TOL * nb2;
        prevB1024 = nb2;
      }
      if (ch) chgflag = 1;                  // benign same-value race
    }
    __syncthreads();                        // S2
    if (chgflag == 0) break;                // identical data in all blocks -> uniform break
    // a gen it+1 = mu / (K b)
    if (it + 1 < SINK_ITERS) {
      const int sn = (it + 1) & 1;
      float acc = k16 * xsB[1024];
#pragma unroll
      for (int q = 0; q < 16; ++q) acc += kr[q] * xsB[l + 64 * q];
#pragma unroll
      for (int off = 32; off > 0; off >>= 1) acc += __shfl_xor(acc, off);
      if (l == 0) { float r = MU / acc; astoref(&av[row], sn ? -r : r); }
      if (extra) {
        float a2 = k216 * xsB[1024];
#pragma unroll
        for (int q = 0; q < 16; ++q) a2 += k2[q] * xsB[l + 64 * q];
#pragma unroll
        for (int off = 32; off > 0; off >>= 1) a2 += __shfl_xor(a2, off);
        if (l == 0) { float r = 0.5f / a2; astoref(&av[1024], sn ? -r : r); }
      }
    }
  }

  // ---- xsB holds final |b|: rinv = 1/(K·b) (ready flag: >= 0, reset -1) ----
  {
    float acc = k16 * xsB[1024];
#pragma unroll
    for (int q = 0; q < 16; ++q) acc += kr[q] * xsB[l + 64 * q];
#pragma unroll
    for (int off = 32; off > 0; off >>= 1) acc += __shfl_xor(acc, off);
    if (l == 0) astoref(&rinvb[row], 1.0f / acc);
    if (extra) {
      float a2 = k216 * xsB[1024];
#pragma unroll
      for (int q = 0; q < 16; ++q) a2 += k2[q] * xsB[l + 64 * q];
#pragma unroll
      for (int off = 32; off > 0; off >>= 1) a2 += __shfl_xor(a2, off);
      if (l == 0) astoref(&rinvb[1024], 1.0f / a2);
    }
  }
  // stage rinv
  rsv[t] = pollp(&rinvb[t]);
  if (t == 0) rsv[1024] = pollp(&rinvb[1024]);
  __syncthreads();

  // ---- S rows + row argmax + col argmax ----
  float* Sbase = out + 4096;
  {
    float ri = rsv[row];
    float* srow = Sbase + (size_t)row * Mm;
    float bm = -1.0f; int bj = 0;
#pragma unroll
    for (int q = 0; q < 16; ++q) {
      int j = l + 64 * q;
      float s = (kr[q] * xsB[j]) * ri;
      srow[j] = s;
      if (s > bm) { bm = s; bj = j; }
    }
    if (l == 0) srow[1024] = (k16 * xsB[1024]) * ri;
#pragma unroll
    for (int off = 32; off > 0; off >>= 1) {
      float om = __shfl_xor(bm, off);
      int oj = __shfl_xor(bj, off);
      if (om > bm || (om == bm && oj < bj)) { bm = om; bj = oj; }
    }
    if (l == 0) { astorei(&idx0[row], bj); astoref(&max0[row], bm); }
    // column argmax for column `row` (bitwise-identical fp expression to S entries)
    float bc = xsB[row];
    float cm = -1.0f; int ci = 0;
#pragma unroll
    for (int q = 0; q < 16; ++q) {
      int i = l + 64 * q;
      float v = (tr[q] * bc) * rsv[i];
      if (v > cm) { cm = v; ci = i; }
    }
#pragma unroll
    for (int off = 32; off > 0; off >>= 1) {
      float om = __shfl_xor(cm, off);
      int oi = __shfl_xor(ci, off);
      if (om > cm || (om == cm && oi < ci)) { cm = om; ci = oi; }
    }
    if (l == 0) astorei(&idx1[row], ci);
    if (extra) {  // S row 1024 (no argmax)
      float ri2 = rsv[1024];
      float* sr2 = Sbase + (size_t)Nn * Mm;
#pragma unroll
      for (int q = 0; q < 16; ++q) {
        int j = l + 64 * q;
        sr2[j] = (k2[q] * xsB[j]) * ri2;
      }
      if (l == 0) sr2[1024] = (k216 * xsB[1024]) * ri2;
    }
  }

  // ---- mutual matching (block 0 polls idx/max ready-flags) ----
  if (bid == 0) {
    int j0  = polli(&idx0[t]);
    int i1v = polli(&idx1[t]);
    float mr = pollp(&max0[t]);
    i0s[t] = j0; i1s[t] = i1v;
    __syncthreads();
    bool mut0 = (i1s[j0] == t);
    float m0 = mut0 ? expf(mr) : 0.0f;   // reference: mscores0 = exp(row max of S)
    bool val0 = mut0 && (m0 > 0.2f);
    msg[t] = m0; v0s[t] = val0 ? 1 : 0;
    out[t] = val0 ? (float)j0 : -1.0f;   // indices0
    out[2048 + t] = m0;                   // mscores0
    __syncthreads();
    bool mut1 = (i0s[i1v] == t);
    float m1 = mut1 ? msg[i1v] : 0.0f;
    bool val1 = mut1 && (v0s[i1v] != 0);
    out[1024 + t] = val1 ? (float)i1v : -1.0f;  // indices1
    out[3072 + t] = m1;                          // mscores1
  }
}

extern "C" void kernel_launch(void* const* d_in, const int* in_sizes, int n_in,
                              void* d_out, int out_size, void* d_ws, size_t ws_size,
                              hipStream_t stream) {
  (void)in_sizes; (void)n_in; (void)out_size; (void)ws_size;
  const float* desc0 = (const float*)d_in[0];
  const float* desc1 = (const float*)d_in[1];
  const float* Wp    = (const float*)d_in[2];
  const float* bp    = (const float*)d_in[3];
  const float* W1    = (const float*)d_in[4];
  const float* b1    = (const float*)d_in[5];
  const float* W2    = (const float*)d_in[6];
  const float* b2    = (const float*)d_in[7];
  const float* Wz1   = (const float*)d_in[8];
  const float* bz1   = (const float*)d_in[9];
  const float* Wz2   = (const float*)d_in[10];
  const float* bz2   = (const float*)d_in[11];
  const float* Wz3   = (const float*)d_in[12];
  const float* bz3   = (const float*)d_in[13];
  float* ws  = (float*)d_ws;
  float* out = (float*)d_out;
  dim3 blk(TPB);

  k_mdesc<<<dim3(4, 64), blk, 0, stream>>>(Wp, bp, desc0, ws + OF_MD0, ws + OF_MD0T);
  k_mdesc<<<dim3(4, 64), blk, 0, stream>>>(Wp, bp, desc1, ws + OF_MD1, ws + OF_MD1T);
  k_h<<<dim3(4, 64, 2), blk, 0, stream>>>(W1, ws + OF_MD0, ws + OF_MD1, ws + OF_HA, ws + OF_HBT);
  k_attn<<<dim3(4, 256), blk, 0, stream>>>(ws + OF_HA, ws + OF_HBT, W2, b1, b2, ws + OF_ATTN);
  k_rowstats<<<dim3(1024), blk, 0, stream>>>(ws + OF_ATTN, ws + OF_ROWM, ws + OF_ROWS);
  k_colpart<<<dim3(4, 16), blk, 0, stream>>>(ws + OF_ATTN, ws + OF_CMP, ws + OF_CSP);
  k_colcomb<<<dim3(4), blk, 0, stream>>>(ws + OF_CMP, ws + OF_CSP, ws + OF_COLM, ws + OF_COLS);
  k_prob<<<dim3(4, 1024), blk, 0, stream>>>(ws + OF_ATTN, ws + OF_ROWM, ws + OF_ROWS,
                                            ws + OF_COLM, ws + OF_COLS,
                                            ws + OF_PROBA, ws + OF_PROBB);
  // attn region is dead now; partials alias it
  k_zfeat_part<<<dim3(256, 2, 2), blk, 0, stream>>>(ws + OF_PROBA, ws + OF_PROBB,
                                                    ws + OF_MD0T, ws + OF_MD1T,
                                                    ws + OF_PART);
  k_zfeat_comb<<<dim3(2048), blk, 0, stream>>>(ws + OF_PART, ws + OF_ZFA, ws + OF_ZFB);
  k_transposeW<<<dim3(320), blk, 0, stream>>>(Wz1, Wz2, ws + OF_WZ1T, ws + OF_WZ2T);
  k_zmlp<<<dim3(1024, 2), blk, 0, stream>>>(ws + OF_ZFA, ws + OF_ZFB,
                                            ws + OF_WZ1T, bz1, ws + OF_WZ2T, bz2,
                                            Wz3, bz3, ws + OF_ZA, ws + OF_ZB);
  // ---- K build (clobbers partials/probA region; both dead) ----
  k_buildK<<<dim3(4, 256), blk, 0, stream>>>(ws + OF_MD0T, ws + OF_MD1,
                                             ws + OF_K, ws + OF_KT);
  k_edgeK<<<dim3(5), blk, 0, stream>>>(ws + OF_ZA, ws + OF_ZB, ws + OF_K, ws + OF_KT,
                                       ws + OF_AV, ws + OF_BV, ws + OF_RINV,
                                       (int*)(ws + OF_IDX0), ws + OF_MAX0,
                                       (int*)(ws + OF_IDX1));
  // ---- dataflow Sinkhorn + fused epilogue (early-exit on convergence) ----
  k_sink_flow2<<<dim3(NB), dim3(PT), 0, stream>>>(
      ws + OF_K, ws + OF_KT, ws + OF_AV, ws + OF_BV, ws + OF_RINV,
      (int*)(ws + OF_IDX0), ws + OF_MAX0, (int*)(ws + OF_IDX1), out);
}

// Round 8
// 208.305 us; speedup vs baseline: 7.0038x; 1.1791x over previous
//
#include <hip/hip_runtime.h>
#include <math.h>

#define TPB 256

constexpr int Dd = 256;
constexpr int Nn = 1024;
constexpr int Mm = 1025;      // Nn + 1 (with dustbin)
constexpr int LDKc = 1040;    // padded row stride for K / KT (16-float aligned)
constexpr int SINK_ITERS = 100;
constexpr int NB  = 64;       // flow blocks
constexpr int PT  = 1024;     // threads per flow block (16 waves, 1 wave = 1 row)

// ---- workspace layout (float offsets) ----
constexpr size_t OF_MD0   = 0;
constexpr size_t OF_MD1   = OF_MD0  + (size_t)Dd*Nn;
constexpr size_t OF_MD0T  = OF_MD1  + (size_t)Dd*Nn;
constexpr size_t OF_MD1T  = OF_MD0T + (size_t)Dd*Nn;
constexpr size_t OF_HA    = OF_MD1T + (size_t)Dd*Nn;
constexpr size_t OF_HBT   = OF_HA   + (size_t)Nn*64;
constexpr size_t OF_WZ1T  = OF_HBT  + (size_t)Nn*64;
constexpr size_t OF_WZ2T  = OF_WZ1T + (size_t)Dd*Dd;
constexpr size_t OF_ZA    = OF_WZ2T + (size_t)64*Dd;
constexpr size_t OF_ZB    = OF_ZA   + Nn;
constexpr size_t OF_ROWM  = OF_ZB   + Nn;
constexpr size_t OF_ROWS  = OF_ROWM + Nn;
constexpr size_t OF_CMP   = OF_ROWS + Nn;        // 16 x 1024 column partial max
constexpr size_t OF_CSP   = OF_CMP  + (size_t)16*Nn;
constexpr size_t OF_COLM  = OF_CSP  + (size_t)16*Nn;
constexpr size_t OF_COLS  = OF_COLM + Nn;
constexpr size_t OF_AV    = OF_COLS + Nn;             // a vector (sign-parity; reset 0)
constexpr size_t OF_BV    = OF_AV   + LDKc;           // b vector (sign-parity; reset 0)
constexpr size_t OF_RINV  = OF_BV   + LDKc;           // 1/rowsum; reset -1, ready >= 0
constexpr size_t OF_IDX0  = OF_RINV + LDKc;           // int; reset -1, ready >= 0
constexpr size_t OF_MAX0  = OF_IDX0 + Nn;             // reset -1, ready >= 0
constexpr size_t OF_IDX1  = OF_MAX0 + Nn;             // int; reset -1
constexpr size_t OF_ATTN  = OF_IDX1 + Nn;
constexpr size_t OF_PART  = OF_ATTN + (size_t)Nn*Nn;  // zfeat partials (4 x 256K floats)
// K/KT alias attn+part region (both dead once buildK runs; launch-order safe)
constexpr size_t OF_K     = OF_ATTN;
constexpr size_t OF_KT    = OF_K + (size_t)Mm*LDKc;

// ---------- agent-scope (coherence-point) access helpers ----------
__device__ __forceinline__ float aloadf(const float* p) {
  return __hip_atomic_load((float*)p, __ATOMIC_RELAXED, __HIP_MEMORY_SCOPE_AGENT);
}
__device__ __forceinline__ int aloadi(const int* p) {
  return __hip_atomic_load((int*)p, __ATOMIC_RELAXED, __HIP_MEMORY_SCOPE_AGENT);
}
__device__ __forceinline__ void astoref(float* p, float v) {
  __hip_atomic_store(p, v, __ATOMIC_RELAXED, __HIP_MEMORY_SCOPE_AGENT);
}
__device__ __forceinline__ void astorei(int* p, int v) {
  __hip_atomic_store(p, v, __ATOMIC_RELAXED, __HIP_MEMORY_SCOPE_AGENT);
}

// one-entry parity poll: the poll IS the data read (0 fails both tests -> "reset")
__device__ __forceinline__ float pollsgn(const float* p, int neg) {
  for (;;) {
    float v = aloadf(p);
    if (neg ? (v < 0.0f) : (v > 0.0f)) return v;
    __builtin_amdgcn_s_sleep(1);
  }
}
__device__ __forceinline__ float pollp(const float* p) {   // ready: >= 0 (reset -1)
  for (;;) {
    float v = aloadf(p);
    if (v >= 0.0f) return v;
    __builtin_amdgcn_s_sleep(1);
  }
}
__device__ __forceinline__ int polli(const int* p) {       // ready: >= 0 (reset -1)
  for (;;) {
    int v = aloadi(p);
    if (v >= 0) return v;
    __builtin_amdgcn_s_sleep(1);
  }
}

// mdesc = Wp @ desc + bp for BOTH descriptors; writes transpose too. grid (4,64,2)
__global__ __launch_bounds__(TPB) void k_mdesc(const float* __restrict__ Wp,
                                               const float* __restrict__ bp,
                                               const float* __restrict__ desc0,
                                               const float* __restrict__ desc1,
                                               float* __restrict__ md0,
                                               float* __restrict__ md0T,
                                               float* __restrict__ md1,
                                               float* __restrict__ md1T) {
  int j = blockIdx.x * TPB + threadIdx.x;
  int d0 = blockIdx.y * 4;
  const float* desc = blockIdx.z ? desc1 : desc0;
  float* md  = blockIdx.z ? md1  : md0;
  float* mdT = blockIdx.z ? md1T : md0T;
  float acc[4] = {0.f, 0.f, 0.f, 0.f};
  for (int k = 0; k < Dd; ++k) {
    float v = desc[(size_t)k * Nn + j];
#pragma unroll
    for (int r = 0; r < 4; ++r) acc[r] += Wp[(size_t)(d0 + r) * Dd + k] * v;
  }
#pragma unroll
  for (int r = 0; r < 4; ++r) {
    acc[r] += bp[d0 + r];
    md[(size_t)(d0 + r) * Nn + j] = acc[r];
  }
  *(float4*)&mdT[(size_t)j * Dd + d0] = make_float4(acc[0], acc[1], acc[2], acc[3]);
}

// hA[n,o] / hBt[o,n]. grid (4,64,2)
__global__ __launch_bounds__(TPB) void k_h(const float* __restrict__ W1,
                                           const float* __restrict__ md0,
                                           const float* __restrict__ md1,
                                           float* __restrict__ hA,
                                           float* __restrict__ hBt) {
  int j = blockIdx.x * TPB + threadIdx.x;
  int o = blockIdx.y;
  int which = blockIdx.z;
  const float* md = which ? md1 : md0;
  const float* w = W1 + (size_t)o * 512 + which * 256;
  float acc = 0.f;
  for (int d = 0; d < Dd; ++d) acc += md[(size_t)d * Nn + j] * w[d];
  if (which == 0) hA[(size_t)j * 64 + o] = acc;
  else            hBt[(size_t)o * Nn + j] = acc;
}

// attn[i,j] = b2 + sum_o W2[o]*relu(hA[i,o]+hBt[o,j]+b1[o]). grid (4,256)
__global__ __launch_bounds__(TPB) void k_attn(const float* __restrict__ hA,
                                              const float* __restrict__ hBt,
                                              const float* __restrict__ W2,
                                              const float* __restrict__ b1,
                                              const float* __restrict__ b2,
                                              float* __restrict__ attn) {
  int j = blockIdx.x * TPB + threadIdx.x;
  int i0 = blockIdx.y * 4;
  float bias = b2[0];
  float acc[4] = {bias, bias, bias, bias};
  for (int o = 0; o < 64; ++o) {
    float hb = hBt[(size_t)o * Nn + j] + b1[o];
    float w = W2[o];
#pragma unroll
    for (int r = 0; r < 4; ++r) {
      float t = hA[(size_t)(i0 + r) * 64 + o] + hb;
      acc[r] += w * fmaxf(t, 0.f);
    }
  }
#pragma unroll
  for (int r = 0; r < 4; ++r) attn[(size_t)(i0 + r) * Nn + j] = acc[r];
}

// merged row softmax stats (blocks 0..1023) + column partial stats (1024..1087)
__global__ __launch_bounds__(TPB) void k_stats(const float* __restrict__ attn,
                                               float* __restrict__ rowM,
                                               float* __restrict__ rowS,
                                               float* __restrict__ cmp,
                                               float* __restrict__ csp) {
  int t = threadIdx.x;
  if (blockIdx.x < 1024) {
    int i = blockIdx.x;
    const float* row = attn + (size_t)i * Nn;
    float m = -INFINITY;
    for (int q = 0; q < 4; ++q) m = fmaxf(m, row[t + q * TPB]);
    __shared__ float red[TPB];
    red[t] = m; __syncthreads();
    for (int s = TPB / 2; s > 0; s >>= 1) {
      if (t < s) red[t] = fmaxf(red[t], red[t + s]);
      __syncthreads();
    }
    m = red[0]; __syncthreads();
    float ssum = 0.f;
    for (int q = 0; q < 4; ++q) ssum += expf(row[t + q * TPB] - m);
    red[t] = ssum; __syncthreads();
    for (int s = TPB / 2; s > 0; s >>= 1) {
      if (t < s) red[t] += red[t + s];
      __syncthreads();
    }
    if (t == 0) { rowM[i] = m; rowS[i] = red[0]; }
  } else {
    int flat = blockIdx.x - 1024;     // 0..63
    int jx = flat & 3, c = flat >> 2;
    int j = jx * TPB + t, i0 = c * 64;
    float m = -INFINITY;
    for (int q = 0; q < 64; ++q) m = fmaxf(m, attn[(size_t)(i0 + q) * Nn + j]);
    float s = 0.f;
    for (int q = 0; q < 64; ++q) s += expf(attn[(size_t)(i0 + q) * Nn + j] - m);
    cmp[(size_t)c * Nn + j] = m;
    csp[(size_t)c * Nn + j] = s;
  }
}

__global__ __launch_bounds__(TPB) void k_colcomb(const float* __restrict__ cmp,
                                                 const float* __restrict__ csp,
                                                 float* __restrict__ colM,
                                                 float* __restrict__ colS) {
  int j = blockIdx.x * TPB + threadIdx.x;
  float m = -INFINITY;
  for (int c = 0; c < 16; ++c) m = fmaxf(m, cmp[(size_t)c * Nn + j]);
  float s = 0.f;
  for (int c = 0; c < 16; ++c) s += csp[(size_t)c * Nn + j] * expf(cmp[(size_t)c * Nn + j] - m);
  colM[j] = m; colS[j] = s;
}

// zfeat partials with ON-THE-FLY prob (exp fused; no prob materialization).
// grid (128, 2, 2): x -> 8-row group, y -> j half, z -> side. P tile in LDS.
__global__ __launch_bounds__(TPB) void k_zfeat_part(const float* __restrict__ attn,
                                                    const float* __restrict__ rowM,
                                                    const float* __restrict__ rowS,
                                                    const float* __restrict__ colM,
                                                    const float* __restrict__ colS,
                                                    const float* __restrict__ md0T,
                                                    const float* __restrict__ md1T,
                                                    float* __restrict__ part) {
  int d = threadIdx.x;
  int r0 = blockIdx.x * 8;
  int jc = blockIdx.y;
  int side = blockIdx.z;
  int j0 = jc * 512;
  __shared__ float P[8][512];
  if (side == 0) {
    // P[r][jj] = probA[r0+r][j0+jj]
    for (int idx = threadIdx.x; idx < 8 * 512; idx += TPB) {
      int r = idx >> 9, jj = idx & 511;
      int i = r0 + r;
      P[r][jj] = expf(attn[(size_t)i * Nn + j0 + jj] - rowM[i]) / rowS[i];
    }
  } else {
    // P[r][ii] = probB[j0+ii][r0+r]
    for (int idx = threadIdx.x; idx < 8 * 512; idx += TPB) {
      int r = idx & 7, ii = idx >> 3;
      int j = r0 + r;
      P[r][ii] = expf(attn[(size_t)(j0 + ii) * Nn + j] - colM[j]) / colS[j];
    }
  }
  __syncthreads();
  const float* mdT = side ? md0T : md1T;
  float acc[8] = {0.f, 0.f, 0.f, 0.f, 0.f, 0.f, 0.f, 0.f};
  for (int jj = 0; jj < 512; ++jj) {
    float mv = mdT[(size_t)(j0 + jj) * Dd + d];
#pragma unroll
    for (int r = 0; r < 8; ++r) acc[r] += P[r][jj] * mv;
  }
  float* dst = part + (size_t)(side * 2 + jc) * ((size_t)Nn * Dd);
#pragma unroll
  for (int r = 0; r < 8; ++r) dst[(size_t)(r0 + r) * Dd + d] = acc[r];
}

// transpose Wz1 (256x256) and Wz2 (64x256). grid 320
__global__ __launch_bounds__(TPB) void k_transposeW(const float* __restrict__ Wz1,
                                                    const float* __restrict__ Wz2,
                                                    float* __restrict__ Wz1T,
                                                    float* __restrict__ Wz2T) {
  int t = threadIdx.x, b = blockIdx.x;
  if (b < 256) Wz1T[(size_t)t * 256 + b] = Wz1[(size_t)b * 256 + t];
  else {
    int o = b - 256;
    Wz2T[(size_t)t * 64 + o] = Wz2[(size_t)o * 256 + t];
  }
}

// zmlp, 8 rows per block (amortizes Wz1T/Wz2T reads 8x); partial-sum fused on load.
// grid (128, 2)
__global__ __launch_bounds__(TPB) void k_zmlp(const float* __restrict__ part,
                                              const float* __restrict__ Wz1T,
                                              const float* __restrict__ bz1,
                                              const float* __restrict__ Wz2T,
                                              const float* __restrict__ bz2,
                                              const float* __restrict__ Wz3,
                                              const float* __restrict__ bz3,
                                              float* __restrict__ zA,
                                              float* __restrict__ zB) {
  int i0 = blockIdx.x * 8;
  int which = blockIdx.y;
  int t = threadIdx.x;
  __shared__ float xs[8][Dd];
  __shared__ float h1[8][Dd];
  __shared__ float h2[8][64];
  const float* p0 = part + (size_t)(which * 2) * ((size_t)Nn * Dd);
  const float* p1 = p0 + (size_t)Nn * Dd;
  for (int idx = t; idx < 8 * Dd; idx += TPB) {
    int r = idx >> 8, d = idx & 255;
    size_t off = (size_t)(i0 + r) * Dd + d;
    xs[r][d] = p0[off] + p1[off];      // == old zfeat_comb, bit-identical
  }
  __syncthreads();
  // layer 1: thread t computes hidden unit t for all 8 rows
  float a1[8];
  float bb = bz1[t];
#pragma unroll
  for (int r = 0; r < 8; ++r) a1[r] = bb;
  for (int k = 0; k < Dd; ++k) {
    float w = Wz1T[(size_t)k * Dd + t];
#pragma unroll
    for (int r = 0; r < 8; ++r) a1[r] += w * xs[r][k];
  }
#pragma unroll
  for (int r = 0; r < 8; ++r) h1[r][t] = fmaxf(a1[r], 0.f);
  __syncthreads();
  // layer 2: thread t -> output o=t&63 for rows rg, rg+1 (rg = (t>>6)*2)
  {
    int o = t & 63, rg = (t >> 6) * 2;
    float b2v = bz2[o];
    float a20 = b2v, a21 = b2v;
    for (int k = 0; k < Dd; ++k) {
      float w = Wz2T[(size_t)k * 64 + o];
      a20 += w * h1[rg][k];
      a21 += w * h1[rg + 1][k];
    }
    h2[rg][o] = fmaxf(a20, 0.f);
    h2[rg + 1][o] = fmaxf(a21, 0.f);
  }
  __syncthreads();
  // layer 3: wave wv reduces rows 2wv, 2wv+1
  int wv = t >> 6, l = t & 63;
  float* z = which ? zB : zA;
#pragma unroll
  for (int s = 0; s < 2; ++s) {
    int r = wv * 2 + s;
    float p = Wz3[l] * h2[r][l];
#pragma unroll
    for (int off = 32; off > 0; off >>= 1) p += __shfl_down(p, off);
    if (l == 0) z[i0 + r] = p + bz3[0];
  }
}

// K[i,j] = exp(scores[i,j]) for i,j<1024, also KT; y==0 blocks also reset sync bufs.
// grid (4,256)
__global__ __launch_bounds__(TPB) void k_buildK(const float* __restrict__ md0T,
                                                const float* __restrict__ md1,
                                                float* __restrict__ K,
                                                float* __restrict__ KT,
                                                float* __restrict__ av,
                                                float* __restrict__ bv,
                                                float* __restrict__ rinvb,
                                                int* __restrict__ idx0,
                                                float* __restrict__ max0,
                                                int* __restrict__ idx1) {
  int j = blockIdx.x * TPB + threadIdx.x;
  int i0 = blockIdx.y * 4;
  if (blockIdx.y == 0) {   // resets (j covers 0..1023 across the 4 x-blocks)
    av[j] = 0.0f; bv[j] = 0.0f; rinvb[j] = -1.0f;
    idx0[j] = -1; idx1[j] = -1; max0[j] = -1.0f;
    if (j == 0) { av[1024] = 0.0f; bv[1024] = 0.0f; rinvb[1024] = -1.0f; }
  }
  float acc[4] = {0.f, 0.f, 0.f, 0.f};
  for (int d = 0; d < Dd; ++d) {
    float mv = md1[(size_t)d * Nn + j];
#pragma unroll
    for (int r = 0; r < 4; ++r) acc[r] += md0T[(size_t)(i0 + r) * Dd + d] * mv;
  }
  float vr[4];
#pragma unroll
  for (int r = 0; r < 4; ++r) {
    vr[r] = expf(acc[r] * 0.0625f);
    K[(size_t)(i0 + r) * LDKc + j] = vr[r];
  }
  *(float4*)&KT[(size_t)j * LDKc + i0] = make_float4(vr[0], vr[1], vr[2], vr[3]);
}

// Dataflow Sinkhorn + fused epilogue + early exit. grid NB x PT.
// Wave w of block b owns row b*16+w (inner K/KT rows in VGPRs); dustbin edge values
// are computed from zA/zB in registers (K/KT edge columns never materialized).
__global__ __launch_bounds__(PT) void k_sink_flow2(
    const float* __restrict__ K, const float* __restrict__ KT,
    const float* __restrict__ zA, const float* __restrict__ zB,
    float* __restrict__ av, float* __restrict__ bv, float* __restrict__ rinvb,
    int* __restrict__ idx0, float* __restrict__ max0, int* __restrict__ idx1,
    float* __restrict__ out) {
  const int bid = blockIdx.x;
  const int t = threadIdx.x;
  const int w = t >> 6, l = t & 63;
  const int row = bid * 16 + w;
  const bool extra = (bid == 0 && w == 0);
  const float MU = 1.0f / 2048.0f;
  const float TOL = 1e-5f;
  const float E1 = 2.7182818284590452f;  // exp(alpha=1)

  const float* kp = K  + (size_t)row * LDKc;
  const float* tp = KT + (size_t)row * LDKc;
  float kr[16], tr[16];
#pragma unroll
  for (int q = 0; q < 16; ++q) { kr[q] = kp[l + 64 * q]; tr[q] = tp[l + 64 * q]; }
  const float k16 = (l == 0) ? expf(zA[row]) : 0.0f;   // K[row][1024]
  const float t16 = (l == 0) ? expf(zB[row]) : 0.0f;   // KT[row][1024] = K[1024][row]
  float k2[16], t2[16];
  float k216 = 0.0f, t216 = 0.0f;
#pragma unroll
  for (int q = 0; q < 16; ++q) { k2[q] = 0.0f; t2[q] = 0.0f; }
  if (extra) {
#pragma unroll
    for (int q = 0; q < 16; ++q) {
      k2[q] = expf(zB[l + 64 * q]);   // K[1024][j]
      t2[q] = expf(zA[l + 64 * q]);   // KT[1024][i] = K[i][1024]
    }
    if (l == 0) { k216 = E1; t216 = E1; }
  }

  __shared__ float xsA[LDKc];
  __shared__ float xsB[LDKc];
  __shared__ float rsv[LDKc];
  __shared__ int   i0s[Nn], i1s[Nn], v0s[Nn];
  __shared__ float msg[Nn];
  __shared__ int   chgflag;

  float prevB = -1.0f, prevB1024 = -1.0f;

  // ---- a gen0 = mu / (K · 1) ----
  {
    float acc = k16;
#pragma unroll
    for (int q = 0; q < 16; ++q) acc += kr[q];
#pragma unroll
    for (int off = 32; off > 0; off >>= 1) acc += __shfl_xor(acc, off);
    if (l == 0) astoref(&av[row], MU / acc);
    if (extra) {
      float a2 = k216;
#pragma unroll
      for (int q = 0; q < 16; ++q) a2 += k2[q];
#pragma unroll
      for (int off = 32; off > 0; off >>= 1) a2 += __shfl_xor(a2, off);
      if (l == 0) astoref(&av[1024], 0.5f / a2);
    }
  }

  for (int it = 0; it < SINK_ITERS; ++it) {
    const int sg = it & 1;
    xsA[t] = fabsf(pollsgn(&av[t], sg));
    if (t == 0) xsA[1024] = fabsf(pollsgn(&av[1024], sg));
    __syncthreads();                        // S1
    if (t == 0) chgflag = 0;
    // b gen it = nu / (KT a)
    {
      float acc = t16 * xsA[1024];
#pragma unroll
      for (int q = 0; q < 16; ++q) acc += tr[q] * xsA[l + 64 * q];
#pragma unroll
      for (int off = 32; off > 0; off >>= 1) acc += __shfl_xor(acc, off);
      if (l == 0) { float r = MU / acc; astoref(&bv[row], sg ? -r : r); }
      if (extra) {
        float a2 = t216 * xsA[1024];
#pragma unroll
        for (int q = 0; q < 16; ++q) a2 += t2[q] * xsA[l + 64 * q];
#pragma unroll
        for (int off = 32; off > 0; off >>= 1) a2 += __shfl_xor(a2, off);
        if (l == 0) { float r = 0.5f / a2; astoref(&bv[1024], sg ? -r : r); }
      }
    }
    // stage |b| + convergence test vs previous iteration
    {
      float nb = fabsf(pollsgn(&bv[t], sg));
      xsB[t] = nb;
      bool ch = fabsf(nb - prevB) > TOL * nb;
      prevB = nb;
      if (t == 0) {
        float nb2 = fabsf(pollsgn(&bv[1024], sg));
        xsB[1024] = nb2;
        ch |= fabsf(nb2 - prevB1024) > TOL * nb2;
        prevB1024 = nb2;
      }
      if (ch) chgflag = 1;                  // benign same-value race
    }
    __syncthreads();                        // S2
    if (chgflag == 0) break;                // identical data everywhere -> uniform break
    // a gen it+1 = mu / (K b)
    if (it + 1 < SINK_ITERS) {
      const int sn = (it + 1) & 1;
      float acc = k16 * xsB[1024];
#pragma unroll
      for (int q = 0; q < 16; ++q) acc += kr[q] * xsB[l + 64 * q];
#pragma unroll
      for (int off = 32; off > 0; off >>= 1) acc += __shfl_xor(acc, off);
      if (l == 0) { float r = MU / acc; astoref(&av[row], sn ? -r : r); }
      if (extra) {
        float a2 = k216 * xsB[1024];
#pragma unroll
        for (int q = 0; q < 16; ++q) a2 += k2[q] * xsB[l + 64 * q];
#pragma unroll
        for (int off = 32; off > 0; off >>= 1) a2 += __shfl_xor(a2, off);
        if (l == 0) { float r = 0.5f / a2; astoref(&av[1024], sn ? -r : r); }
      }
    }
  }

  // ---- rinv = 1/(K·b) ----
  {
    float acc = k16 * xsB[1024];
#pragma unroll
    for (int q = 0; q < 16; ++q) acc += kr[q] * xsB[l + 64 * q];
#pragma unroll
    for (int off = 32; off > 0; off >>= 1) acc += __shfl_xor(acc, off);
    if (l == 0) astoref(&rinvb[row], 1.0f / acc);
    if (extra) {
      float a2 = k216 * xsB[1024];
#pragma unroll
      for (int q = 0; q < 16; ++q) a2 += k2[q] * xsB[l + 64 * q];
#pragma unroll
      for (int off = 32; off > 0; off >>= 1) a2 += __shfl_xor(a2, off);
      if (l == 0) astoref(&rinvb[1024], 1.0f / a2);
    }
  }
  rsv[t] = pollp(&rinvb[t]);
  if (t == 0) rsv[1024] = pollp(&rinvb[1024]);
  __syncthreads();

  // ---- S rows + row argmax + col argmax ----
  float* Sbase = out + 4096;
  {
    float ri = rsv[row];
    float* srow = Sbase + (size_t)row * Mm;
    float bm = -1.0f; int bj = 0;
#pragma unroll
    for (int q = 0; q < 16; ++q) {
      int j = l + 64 * q;
      float s = (kr[q] * xsB[j]) * ri;
      srow[j] = s;
      if (s > bm) { bm = s; bj = j; }
    }
    if (l == 0) srow[1024] = (k16 * xsB[1024]) * ri;
#pragma unroll
    for (int off = 32; off > 0; off >>= 1) {
      float om = __shfl_xor(bm, off);
      int oj = __shfl_xor(bj, off);
      if (om > bm || (om == bm && oj < bj)) { bm = om; bj = oj; }
    }
    if (l == 0) { astorei(&idx0[row], bj); astoref(&max0[row], bm); }
    float bc = xsB[row];
    float cm = -1.0f; int ci = 0;
#pragma unroll
    for (int q = 0; q < 16; ++q) {
      int i = l + 64 * q;
      float v = (tr[q] * bc) * rsv[i];
      if (v > cm) { cm = v; ci = i; }
    }
#pragma unroll
    for (int off = 32; off > 0; off >>= 1) {
      float om = __shfl_xor(cm, off);
      int oi = __shfl_xor(ci, off);
      if (om > cm || (om == cm && oi < ci)) { cm = om; ci = oi; }
    }
    if (l == 0) astorei(&idx1[row], ci);
    if (extra) {  // S row 1024
      float ri2 = rsv[1024];
      float* sr2 = Sbase + (size_t)Nn * Mm;
#pragma unroll
      for (int q = 0; q < 16; ++q) {
        int j = l + 64 * q;
        sr2[j] = (k2[q] * xsB[j]) * ri2;
      }
      if (l == 0) sr2[1024] = (k216 * xsB[1024]) * ri2;
    }
  }

  // ---- mutual matching (block 0) ----
  if (bid == 0) {
    int j0  = polli(&idx0[t]);
    int i1v = polli(&idx1[t]);
    float mr = pollp(&max0[t]);
    i0s[t] = j0; i1s[t] = i1v;
    __syncthreads();
    bool mut0 = (i1s[j0] == t);
    float m0 = mut0 ? expf(mr) : 0.0f;
    bool val0 = mut0 && (m0 > 0.2f);
    msg[t] = m0; v0s[t] = val0 ? 1 : 0;
    out[t] = val0 ? (float)j0 : -1.0f;   // indices0
    out[2048 + t] = m0;                   // mscores0
    __syncthreads();
    bool mut1 = (i0s[i1v] == t);
    float m1 = mut1 ? msg[i1v] : 0.0f;
    bool val1 = mut1 && (v0s[i1v] != 0);
    out[1024 + t] = val1 ? (float)i1v : -1.0f;  // indices1
    out[3072 + t] = m1;                          // mscores1
  }
}

extern "C" void kernel_launch(void* const* d_in, const int* in_sizes, int n_in,
                              void* d_out, int out_size, void* d_ws, size_t ws_size,
                              hipStream_t stream) {
  (void)in_sizes; (void)n_in; (void)out_size; (void)ws_size;
  const float* desc0 = (const float*)d_in[0];
  const float* desc1 = (const float*)d_in[1];
  const float* Wp    = (const float*)d_in[2];
  const float* bp    = (const float*)d_in[3];
  const float* W1    = (const float*)d_in[4];
  const float* b1    = (const float*)d_in[5];
  const float* W2    = (const float*)d_in[6];
  const float* b2    = (const float*)d_in[7];
  const float* Wz1   = (const float*)d_in[8];
  const float* bz1   = (const float*)d_in[9];
  const float* Wz2   = (const float*)d_in[10];
  const float* bz2   = (const float*)d_in[11];
  const float* Wz3   = (const float*)d_in[12];
  const float* bz3   = (const float*)d_in[13];
  float* ws  = (float*)d_ws;
  float* out = (float*)d_out;
  dim3 blk(TPB);

  k_mdesc<<<dim3(4, 64, 2), blk, 0, stream>>>(Wp, bp, desc0, desc1,
                                              ws + OF_MD0, ws + OF_MD0T,
                                              ws + OF_MD1, ws + OF_MD1T);
  k_h<<<dim3(4, 64, 2), blk, 0, stream>>>(W1, ws + OF_MD0, ws + OF_MD1,
                                          ws + OF_HA, ws + OF_HBT);
  k_attn<<<dim3(4, 256), blk, 0, stream>>>(ws + OF_HA, ws + OF_HBT, W2, b1, b2,
                                           ws + OF_ATTN);
  k_stats<<<dim3(1088), blk, 0, stream>>>(ws + OF_ATTN, ws + OF_ROWM, ws + OF_ROWS,
                                          ws + OF_CMP, ws + OF_CSP);
  k_colcomb<<<dim3(4), blk, 0, stream>>>(ws + OF_CMP, ws + OF_CSP,
                                         ws + OF_COLM, ws + OF_COLS);
  k_zfeat_part<<<dim3(128, 2, 2), blk, 0, stream>>>(ws + OF_ATTN,
                                                    ws + OF_ROWM, ws + OF_ROWS,
                                                    ws + OF_COLM, ws + OF_COLS,
                                                    ws + OF_MD0T, ws + OF_MD1T,
                                                    ws + OF_PART);
  k_transposeW<<<dim3(320), blk, 0, stream>>>(Wz1, Wz2, ws + OF_WZ1T, ws + OF_WZ2T);
  k_zmlp<<<dim3(128, 2), blk, 0, stream>>>(ws + OF_PART, ws + OF_WZ1T, bz1,
                                           ws + OF_WZ2T, bz2, Wz3, bz3,
                                           ws + OF_ZA, ws + OF_ZB);
  // buildK clobbers attn/part region (both dead) + resets sync buffers
  k_buildK<<<dim3(4, 256), blk, 0, stream>>>(ws + OF_MD0T, ws + OF_MD1,
                                             ws + OF_K, ws + OF_KT,
                                             ws + OF_AV, ws + OF_BV, ws + OF_RINV,
                                             (int*)(ws + OF_IDX0), ws + OF_MAX0,
                                             (int*)(ws + OF_IDX1));
  k_sink_flow2<<<dim3(NB), dim3(PT), 0, stream>>>(
      ws + OF_K, ws + OF_KT, ws + OF_ZA, ws + OF_ZB,
      ws + OF_AV, ws + OF_BV, ws + OF_RINV,
      (int*)(ws + OF_IDX0), ws + OF_MAX0, (int*)(ws + OF_IDX1), out);
}